// Round 1
// 349.328 us; speedup vs baseline: 1.0137x; 1.0137x over previous
//
#include <hip/hip_runtime.h>
#include <hip/hip_bf16.h>

// Attention_919123001813 — B=4, N=2048, DIM=1024, H=16, HD=64, SCALE=1/8
// Round 11: attn is VALU-issue-bound (VALUBusy 63%, MfmaUtil 19%, combined
// issue ~82%). Cut VALU per 32-key iter from ~45 to ~18 instrs:
//  (a) fold SCALE*log2e into Q inside the QKV-GEMM epilogue (fp32, pre-bf16
//      store => zero precision cost); p = v_exp_f32(s) directly, no muls.
//  (b) softmax denominator l via a 9th MFMA against a ones-fragment (moves
//      7 adds/iter to the idle MFMA pipe, kills epilogue shuffle reduce).
//  (c) kpack+vpack merged into one kvpack stream; mid-group base pointer so
//      all 8 frag loads are signed-imm offsets off ONE incremented pointer.
//  (d) loop-invariant zero quad for s0/s1 MFMA C-operand (no per-iter movs).

typedef short bf16x8 __attribute__((ext_vector_type(8)));
typedef float f32x4  __attribute__((ext_vector_type(4)));

#define BN   4
#define SEQ  2048
#define CDIM 1024
#define NH   16
#define HD   64
#define QKVN 3072
#define MTOT 8192   // BN*SEQ
// SCALE * log2(e) — folded into Q columns of the QKV GEMM output (fp32).
#define QSCALE_LOG2E 0.18033688011112042f

static __device__ __forceinline__ unsigned short f2bf(float f){
    union { float f; unsigned int i; } v; v.f = f;
    unsigned int r = v.i + 0x7FFFu + ((v.i >> 16) & 1u);   // RNE
    return (unsigned short)(r >> 16);
}

// two fp32 -> one dword of packed bf16 (RNE). gfx950: single v_cvt_pk_bf16_f32.
static __device__ __forceinline__ unsigned int pk2bf(float a, float b){
#if __has_builtin(__builtin_amdgcn_cvt_pk_bf16_f32)
    auto r = __builtin_amdgcn_cvt_pk_bf16_f32(a, b);
    unsigned int u; __builtin_memcpy(&u, &r, 4); return u;
#else
    return (unsigned int)f2bf(a) | ((unsigned int)f2bf(b) << 16);
#endif
}

// raw 2^x (v_exp_f32). Q already carries the SCALE*log2e factor.
static __device__ __forceinline__ float fast_exp2(float x){
#if __has_builtin(__builtin_amdgcn_exp2f)
    return __builtin_amdgcn_exp2f(x);
#else
    return __expf(x * 0.69314718055994531f);
#endif
}

typedef __attribute__((address_space(3))) unsigned int        as3_uint;
typedef const __attribute__((address_space(1))) unsigned int  as1_uint;
static __device__ __forceinline__ void load_lds16(
    const unsigned short* g, unsigned short* l)
{
    __builtin_amdgcn_global_load_lds((as1_uint*)g, (as3_uint*)l, 16, 0, 0);
}

// ---------------- elementwise fp32 -> bf16 (8 elems/thread) ----------------
__global__ __launch_bounds__(256) void convert_f32_bf16(
    const float* __restrict__ in, unsigned short* __restrict__ out)
{
    size_t i = ((size_t)blockIdx.x * 256 + threadIdx.x) * 8;
    f32x4 a = *(const f32x4*)(in + i);
    f32x4 b = *(const f32x4*)(in + i + 4);
    union { unsigned int u[4]; bf16x8 v; } o;
    o.u[0] = pk2bf(a[0], a[1]); o.u[1] = pk2bf(a[2], a[3]);
    o.u[2] = pk2bf(b[0], b[1]); o.u[3] = pk2bf(b[2], b[3]);
    *(bf16x8*)(out + i) = o.v;
}

// ---------------- 32x32 tiled transpose: fp32 in -> bf16 out ---------------
__global__ __launch_bounds__(256) void transpose_f32_to_bf16(
    const float* __restrict__ in, unsigned short* __restrict__ out,
    int in_rs, int out_rs)
{
    __shared__ unsigned short tile[32][33];
    int c0 = blockIdx.x * 32, r0 = blockIdx.y * 32;
    int tx = threadIdx.x, ty = threadIdx.y;
    #pragma unroll
    for (int j = 0; j < 4; j++)
        tile[ty + 8*j][tx] = f2bf(in[(long long)(r0 + ty + 8*j) * in_rs + c0 + tx]);
    __syncthreads();
    #pragma unroll
    for (int j = 0; j < 4; j++)
        out[(long long)(c0 + ty + 8*j) * out_rs + r0 + tx] = tile[tx][ty + 8*j];
}

// ---------------- pack K into fragment order (frags 0..3 of kvpack) --------
__global__ __launch_bounds__(256) void pack_k(
    const unsigned short* __restrict__ qkv, unsigned short* __restrict__ kvpack)
{
    int blk = blockIdx.x;            // bh*64 + t
    int bh = blk >> 6, t = blk & 63;
    int b = bh >> 4, h = bh & 15;
    int tid = threadIdx.x;
    int fr = tid >> 6, l = tid & 63;
    int quad = l >> 4, l15 = l & 15;
    int tb = fr >> 1, d32 = (fr & 1) * 32;
    int row = b*SEQ + t*32 + (l15 >> 2)*8 + (l15 & 3) + 4*tb;
    bf16x8 v = *(const bf16x8*)(qkv + (size_t)row * QKVN + CDIM + h*HD + d32 + quad*8);
    *(bf16x8*)(kvpack + ((size_t)blk*8 + fr)*512 + (size_t)l*8) = v;
}

// ---------------- pack V into fragment order (frags 4..7 of kvpack) --------
__global__ __launch_bounds__(256) void pack_v(
    const unsigned short* __restrict__ qkv, unsigned short* __restrict__ vpack)
{
    __shared__ unsigned short tile[32][66];
    int blk = blockIdx.x;            // bh*64 + t
    int bh = blk >> 6, t = blk & 63;
    int b = bh >> 4, h = bh & 15;
    int tid = threadIdx.x;
    int kk = tid >> 3, dd8 = (tid & 7) * 8;
    bf16x8 v = *(const bf16x8*)(qkv + (size_t)(b*SEQ + t*32 + kk) * QKVN
                                + 2*CDIM + h*HD + dd8);
    #pragma unroll
    for (int e = 0; e < 8; e++) tile[kk][dd8 + e] = v[e];
    __syncthreads();
    int db = tid >> 6, quad = (tid >> 4) & 3, l15 = tid & 15;
    bf16x8 o;
    #pragma unroll
    for (int e = 0; e < 8; e++) o[e] = tile[quad*8 + e][db*16 + l15];
    *(bf16x8*)(vpack + ((size_t)blk*8 + 4 + db)*512 + (size_t)(quad*16 + l15)*8) = o;
}

// ---------------- m97-style LDS-staged GEMM (R8, verified) -----------------
// qcols/qscale: columns [0, qcols) of the output are scaled by qscale in fp32
// BEFORE the bf16 store (used to fold SCALE*log2e into Q at zero precision
// cost). qcols=0 disables.
template<bool OUTF32>
__global__ __launch_bounds__(256) void gemm_lds(
    const unsigned short* __restrict__ A,    // [M,K] bf16
    const unsigned short* __restrict__ BT,   // [N,K] bf16
    void* __restrict__ Cv,                   // [M,Cstride]
    const float* __restrict__ bias,          // [N] or nullptr
    int K, int Cstride, int qcols, float qscale)
{
    __shared__ unsigned short a_lds[128*32];
    __shared__ unsigned short b_lds[128*32];

    int tid  = threadIdx.x;
    int wave = tid >> 6, lane = tid & 63, quad = lane >> 4, l15 = lane & 15;
    int m_blk = blockIdx.y * 128, n_blk = blockIdx.x * 128;

    const unsigned short* ag = A  + (size_t)(m_blk + (tid >> 2)) * K + (tid & 3)*8;
    const unsigned short* bg = BT + (size_t)(n_blk + (tid >> 2)) * K + (tid & 3)*8;
    const size_t row64 = (size_t)64 * K;

    unsigned short* afr = a_lds + ((wave & 1)*64 + l15)*32 + quad*8;
    unsigned short* bfr = b_lds + ((wave >> 1)*64 + l15)*32 + quad*8;

    f32x4 acc[4][4];
    #pragma unroll
    for (int i = 0; i < 4; i++)
        #pragma unroll
        for (int j = 0; j < 4; j++)
            acc[i][j] = f32x4{0.f, 0.f, 0.f, 0.f};

    for (int k0 = 0; k0 < K; k0 += 32) {
        __syncthreads();
        load_lds16(ag,         a_lds + (size_t)tid*8);
        load_lds16(ag + row64, a_lds + 2048 + (size_t)tid*8);
        load_lds16(bg,         b_lds + (size_t)tid*8);
        load_lds16(bg + row64, b_lds + 2048 + (size_t)tid*8);
        ag += 32; bg += 32;
        __syncthreads();

        bf16x8 af[4], bf[4];
        #pragma unroll
        for (int i = 0; i < 4; i++) af[i] = *(const bf16x8*)(afr + 16*i*32);
        #pragma unroll
        for (int i = 0; i < 4; i++) bf[i] = *(const bf16x8*)(bfr + 16*i*32);

        #pragma unroll
        for (int mi = 0; mi < 4; mi++)
            #pragma unroll
            for (int ni = 0; ni < 4; ni++)
                acc[mi][ni] = __builtin_amdgcn_mfma_f32_16x16x32_bf16(
                                  af[mi], bf[ni], acc[mi][ni], 0, 0, 0);
    }

    int m0 = m_blk + (wave & 1) * 64;
    int n0 = n_blk + (wave >> 1) * 64;
    #pragma unroll
    for (int ni = 0; ni < 4; ni++) {
        int col = n0 + 16*ni + l15;
        float bv = bias ? bias[col] : 0.f;
        #pragma unroll
        for (int mi = 0; mi < 4; mi++)
            #pragma unroll
            for (int r = 0; r < 4; r++) {
                int row = m0 + 16*mi + quad*4 + r;
                float v = acc[mi][ni][r] + bv;
                if (col < qcols) v *= qscale;
                if (OUTF32) ((float*)Cv)[(size_t)row * Cstride + col] = v;
                else ((unsigned short*)Cv)[(size_t)row * Cstride + col] = f2bf(v);
            }
    }
}

// ---------------- Flash attention, unnormalized-softmax --------------------
// One wave per 16-row Q strip, 32 keys/iter from one interleaved kvpack
// stream. Q columns already carry SCALE*log2e, so p = 2^s (raw v_exp_f32,
// no VALU muls). Denominator l accumulated by a 9th MFMA against a ones
// B-fragment: lacc[r] = rowsum for row quad*4+r (every lane), so the
// epilogue needs no shuffles.
__global__ __launch_bounds__(256) void attn_kernel(
    const unsigned short* __restrict__ qkv,    // [MTOT, 3072] (Q cols used)
    const unsigned short* __restrict__ kvpack, // [64 bh][64 t][8 fr][512]
    unsigned short* __restrict__ ctx)          // [MTOT, 1024]
{
    int tid  = threadIdx.x;
    int wave = tid >> 6, lane = tid & 63, quad = lane >> 4, l15 = lane & 15;
    int gw    = blockIdx.x * 4 + wave;
    int bh    = gw >> 7;
    int strip = gw & 127;
    int b = bh >> 4, h = bh & 15;
    int i0 = strip * 16;

    const unsigned short* qbase =
        qkv + (size_t)(b*SEQ + i0 + l15) * QKVN + h*HD + quad*8;
    bf16x8 qf0 = *(const bf16x8*)(qbase);
    bf16x8 qf1 = *(const bf16x8*)(qbase + 32);

    // mid-group base: all 8 fragment loads use signed 13-bit imm offsets
    // (-4096..+3072 bytes); one pointer increment of 8192 B per iter.
    const unsigned short* kv =
        kvpack + (size_t)bh * 64 * 4096 + 2048 + (size_t)lane * 8;

    const f32x4 zf = {0.f, 0.f, 0.f, 0.f};
    f32x4 o[4];
    #pragma unroll
    for (int i = 0; i < 4; i++) o[i] = zf;
    f32x4 lacc = zf;

    bf16x8 ones;          // bf16 1.0 everywhere — B-operand for rowsum MFMA
    #pragma unroll
    for (int e = 0; e < 8; e++) ones[e] = (short)0x3F80;

    for (int t = 0; t < SEQ/32; t++) {
        bf16x8 k0a = *(const bf16x8*)(kv - 2048);
        bf16x8 k0b = *(const bf16x8*)(kv - 1536);
        bf16x8 k1a = *(const bf16x8*)(kv - 1024);
        bf16x8 k1b = *(const bf16x8*)(kv - 512);
        bf16x8 vf0 = *(const bf16x8*)(kv);
        bf16x8 vf1 = *(const bf16x8*)(kv + 512);
        bf16x8 vf2 = *(const bf16x8*)(kv + 1024);
        bf16x8 vf3 = *(const bf16x8*)(kv + 1536);
        kv += 4096;

        f32x4 s0 = __builtin_amdgcn_mfma_f32_16x16x32_bf16(k0a, qf0, zf, 0, 0, 0);
        s0       = __builtin_amdgcn_mfma_f32_16x16x32_bf16(k0b, qf1, s0, 0, 0, 0);
        f32x4 s1 = __builtin_amdgcn_mfma_f32_16x16x32_bf16(k1a, qf0, zf, 0, 0, 0);
        s1       = __builtin_amdgcn_mfma_f32_16x16x32_bf16(k1b, qf1, s1, 0, 0, 0);
        // lane holds S[i=l15][key t*32+quad*8+r] (s0) and [.. +4+r] (s1),
        // already scaled by SCALE*log2e via the Q columns.

        float p[8];
        #pragma unroll
        for (int r = 0; r < 4; r++) {
            p[r]   = fast_exp2(s0[r]);
            p[4+r] = fast_exp2(s1[r]);
        }

        union { unsigned int u[4]; bf16x8 v; } pk;   // A[m=l15][k=quad*8+j]
        pk.u[0] = pk2bf(p[0], p[1]);
        pk.u[1] = pk2bf(p[2], p[3]);
        pk.u[2] = pk2bf(p[4], p[5]);
        pk.u[3] = pk2bf(p[6], p[7]);

        lacc  = __builtin_amdgcn_mfma_f32_16x16x32_bf16(pk.v, ones, lacc, 0, 0, 0);
        o[0]  = __builtin_amdgcn_mfma_f32_16x16x32_bf16(pk.v, vf0, o[0], 0, 0, 0);
        o[1]  = __builtin_amdgcn_mfma_f32_16x16x32_bf16(pk.v, vf1, o[1], 0, 0, 0);
        o[2]  = __builtin_amdgcn_mfma_f32_16x16x32_bf16(pk.v, vf2, o[2], 0, 0, 0);
        o[3]  = __builtin_amdgcn_mfma_f32_16x16x32_bf16(pk.v, vf3, o[3], 0, 0, 0);
    }

    // epilogue: lacc[r] = full row sum for row quad*4+r (same in every lane)
    #pragma unroll
    for (int r = 0; r < 4; r++) {
        float inv = 1.f / lacc[r];
        int row = b*SEQ + i0 + quad*4 + r;
        #pragma unroll
        for (int db = 0; db < 4; db++)
            ctx[(size_t)row * CDIM + h*HD + db*16 + l15] = f2bf(o[db][r] * inv);
    }
}

// ---------------------------------------------------------------------------
extern "C" void kernel_launch(void* const* d_in, const int* in_sizes, int n_in,
                              void* d_out, int out_size, void* d_ws, size_t ws_size,
                              hipStream_t stream)
{
    const float* x      = (const float*)d_in[0]; // [8192,1024] fp32
    const float* w_qkv  = (const float*)d_in[1]; // [1024,3072] fp32
    const float* w_proj = (const float*)d_in[2]; // [1024,1024] fp32
    const float* b_proj = (const float*)d_in[3]; // [1024]      fp32
    float* out = (float*)d_out;                  // [8192,1024] fp32

    char* ws = (char*)d_ws;                                      // 104 MiB used
    unsigned short* qkv    = (unsigned short*)(ws);              // [0,48M)
    unsigned short* ctx    = (unsigned short*)(ws + 50331648);   // [48M,64M)
    unsigned short* kvpack = (unsigned short*)(ws + 67108864);   // [64M,96M)
    unsigned short* xb     = (unsigned short*)(ws + 83886080);   // alias: xb dead
                                                                 // before pack_* write
    unsigned short* wqkvT  = (unsigned short*)(ws + 100663296);  // [96M,102M)
    unsigned short* wprojT = (unsigned short*)(ws + 106954752);  // [102M,104M)

    dim3 tb(32, 8);
    transpose_f32_to_bf16<<<dim3(QKVN/32, CDIM/32), tb, 0, stream>>>(
        w_qkv, wqkvT, QKVN, CDIM);
    transpose_f32_to_bf16<<<dim3(CDIM/32, CDIM/32), tb, 0, stream>>>(
        w_proj, wprojT, CDIM, CDIM);

    // xb = bf16(x)
    convert_f32_bf16<<<dim3(MTOT*CDIM/2048), 256, 0, stream>>>(x, xb);

    // qkv = xb @ wqkvT   [8192, 3072] bf16; Q cols pre-scaled by SCALE*log2e
    gemm_lds<false><<<dim3(QKVN/128, MTOT/128), 256, 0, stream>>>(
        xb, wqkvT, qkv, nullptr, CDIM, QKVN, CDIM, QSCALE_LOG2E);

    // pack K and V into fragment-consumption order (overwrites xb region)
    pack_k<<<dim3(64*64), 256, 0, stream>>>(qkv, kvpack);
    pack_v<<<dim3(64*64), 256, 0, stream>>>(qkv, kvpack);

    // flash attention -> ctx [8192, 1024] bf16
    attn_kernel<<<dim3(BN * NH * (SEQ/16) / 4), 256, 0, stream>>>(
        qkv, kvpack, ctx);

    // out = ctx @ wprojT + b_proj   (fp32 out)
    gemm_lds<true><<<dim3(CDIM/128, MTOT/128), 256, 0, stream>>>(
        ctx, wprojT, out, b_proj, CDIM, CDIM, 0, 1.0f);
}

// Round 2
// 301.764 us; speedup vs baseline: 1.1735x; 1.1576x over previous
//
#include <hip/hip_runtime.h>
#include <hip/hip_bf16.h>

// Attention_919123001813 — B=4, N=2048, DIM=1024, H=16, HD=64, SCALE=1/8
// Round 12: R11 cut VALU (63->42%) but dur barely moved -> not VALU-bound.
// Real limit: L2 bandwidth. 8192 waves x 512KiB KV stream = 4.3GB / 152us
// = 28 TB/s ~ 82% of the 34.5 TB/s L2 ceiling (FETCH_SIZE shows 97% of
// reads are cache hits). Fix: register-block 32 Q rows per wave (2 strips)
// so each KV fragment load feeds 2x the MFMA work -> KV L2 traffic halves.
// 18 MFMA per 32-key iter (8 QK + 8 PV + 2 rowsum) vs 9 before, same loads.
// __launch_bounds__(256,4) pins VGPR<=128 -> 4 waves/SIMD full residency
// (1024 blocks = 4 blocks/CU exactly).

typedef short bf16x8 __attribute__((ext_vector_type(8)));
typedef float f32x4  __attribute__((ext_vector_type(4)));

#define BN   4
#define SEQ  2048
#define CDIM 1024
#define NH   16
#define HD   64
#define QKVN 3072
#define MTOT 8192   // BN*SEQ
// SCALE * log2(e) — folded into Q columns of the QKV GEMM output (fp32).
#define QSCALE_LOG2E 0.18033688011112042f

static __device__ __forceinline__ unsigned short f2bf(float f){
    union { float f; unsigned int i; } v; v.f = f;
    unsigned int r = v.i + 0x7FFFu + ((v.i >> 16) & 1u);   // RNE
    return (unsigned short)(r >> 16);
}

// two fp32 -> one dword of packed bf16 (RNE). gfx950: single v_cvt_pk_bf16_f32.
static __device__ __forceinline__ unsigned int pk2bf(float a, float b){
#if __has_builtin(__builtin_amdgcn_cvt_pk_bf16_f32)
    auto r = __builtin_amdgcn_cvt_pk_bf16_f32(a, b);
    unsigned int u; __builtin_memcpy(&u, &r, 4); return u;
#else
    return (unsigned int)f2bf(a) | ((unsigned int)f2bf(b) << 16);
#endif
}

// raw 2^x (v_exp_f32). Q already carries the SCALE*log2e factor.
static __device__ __forceinline__ float fast_exp2(float x){
#if __has_builtin(__builtin_amdgcn_exp2f)
    return __builtin_amdgcn_exp2f(x);
#else
    return __expf(x * 0.69314718055994531f);
#endif
}

typedef __attribute__((address_space(3))) unsigned int        as3_uint;
typedef const __attribute__((address_space(1))) unsigned int  as1_uint;
static __device__ __forceinline__ void load_lds16(
    const unsigned short* g, unsigned short* l)
{
    __builtin_amdgcn_global_load_lds((as1_uint*)g, (as3_uint*)l, 16, 0, 0);
}

// ---------------- elementwise fp32 -> bf16 (8 elems/thread) ----------------
__global__ __launch_bounds__(256) void convert_f32_bf16(
    const float* __restrict__ in, unsigned short* __restrict__ out)
{
    size_t i = ((size_t)blockIdx.x * 256 + threadIdx.x) * 8;
    f32x4 a = *(const f32x4*)(in + i);
    f32x4 b = *(const f32x4*)(in + i + 4);
    union { unsigned int u[4]; bf16x8 v; } o;
    o.u[0] = pk2bf(a[0], a[1]); o.u[1] = pk2bf(a[2], a[3]);
    o.u[2] = pk2bf(b[0], b[1]); o.u[3] = pk2bf(b[2], b[3]);
    *(bf16x8*)(out + i) = o.v;
}

// ---------------- 32x32 tiled transpose: fp32 in -> bf16 out ---------------
__global__ __launch_bounds__(256) void transpose_f32_to_bf16(
    const float* __restrict__ in, unsigned short* __restrict__ out,
    int in_rs, int out_rs)
{
    __shared__ unsigned short tile[32][33];
    int c0 = blockIdx.x * 32, r0 = blockIdx.y * 32;
    int tx = threadIdx.x, ty = threadIdx.y;
    #pragma unroll
    for (int j = 0; j < 4; j++)
        tile[ty + 8*j][tx] = f2bf(in[(long long)(r0 + ty + 8*j) * in_rs + c0 + tx]);
    __syncthreads();
    #pragma unroll
    for (int j = 0; j < 4; j++)
        out[(long long)(c0 + ty + 8*j) * out_rs + r0 + tx] = tile[tx][ty + 8*j];
}

// ---------------- pack K into fragment order (frags 0..3 of kvpack) --------
__global__ __launch_bounds__(256) void pack_k(
    const unsigned short* __restrict__ qkv, unsigned short* __restrict__ kvpack)
{
    int blk = blockIdx.x;            // bh*64 + t
    int bh = blk >> 6, t = blk & 63;
    int b = bh >> 4, h = bh & 15;
    int tid = threadIdx.x;
    int fr = tid >> 6, l = tid & 63;
    int quad = l >> 4, l15 = l & 15;
    int tb = fr >> 1, d32 = (fr & 1) * 32;
    int row = b*SEQ + t*32 + (l15 >> 2)*8 + (l15 & 3) + 4*tb;
    bf16x8 v = *(const bf16x8*)(qkv + (size_t)row * QKVN + CDIM + h*HD + d32 + quad*8);
    *(bf16x8*)(kvpack + ((size_t)blk*8 + fr)*512 + (size_t)l*8) = v;
}

// ---------------- pack V into fragment order (frags 4..7 of kvpack) --------
__global__ __launch_bounds__(256) void pack_v(
    const unsigned short* __restrict__ qkv, unsigned short* __restrict__ vpack)
{
    __shared__ unsigned short tile[32][66];
    int blk = blockIdx.x;            // bh*64 + t
    int bh = blk >> 6, t = blk & 63;
    int b = bh >> 4, h = bh & 15;
    int tid = threadIdx.x;
    int kk = tid >> 3, dd8 = (tid & 7) * 8;
    bf16x8 v = *(const bf16x8*)(qkv + (size_t)(b*SEQ + t*32 + kk) * QKVN
                                + 2*CDIM + h*HD + dd8);
    #pragma unroll
    for (int e = 0; e < 8; e++) tile[kk][dd8 + e] = v[e];
    __syncthreads();
    int db = tid >> 6, quad = (tid >> 4) & 3, l15 = tid & 15;
    bf16x8 o;
    #pragma unroll
    for (int e = 0; e < 8; e++) o[e] = tile[quad*8 + e][db*16 + l15];
    *(bf16x8*)(vpack + ((size_t)blk*8 + 4 + db)*512 + (size_t)(quad*16 + l15)*8) = o;
}

// ---------------- m97-style LDS-staged GEMM (R8, verified) -----------------
// qcols/qscale: columns [0, qcols) of the output are scaled by qscale in fp32
// BEFORE the bf16 store (used to fold SCALE*log2e into Q at zero precision
// cost). qcols=0 disables.
template<bool OUTF32>
__global__ __launch_bounds__(256) void gemm_lds(
    const unsigned short* __restrict__ A,    // [M,K] bf16
    const unsigned short* __restrict__ BT,   // [N,K] bf16
    void* __restrict__ Cv,                   // [M,Cstride]
    const float* __restrict__ bias,          // [N] or nullptr
    int K, int Cstride, int qcols, float qscale)
{
    __shared__ unsigned short a_lds[128*32];
    __shared__ unsigned short b_lds[128*32];

    int tid  = threadIdx.x;
    int wave = tid >> 6, lane = tid & 63, quad = lane >> 4, l15 = lane & 15;
    int m_blk = blockIdx.y * 128, n_blk = blockIdx.x * 128;

    const unsigned short* ag = A  + (size_t)(m_blk + (tid >> 2)) * K + (tid & 3)*8;
    const unsigned short* bg = BT + (size_t)(n_blk + (tid >> 2)) * K + (tid & 3)*8;
    const size_t row64 = (size_t)64 * K;

    unsigned short* afr = a_lds + ((wave & 1)*64 + l15)*32 + quad*8;
    unsigned short* bfr = b_lds + ((wave >> 1)*64 + l15)*32 + quad*8;

    f32x4 acc[4][4];
    #pragma unroll
    for (int i = 0; i < 4; i++)
        #pragma unroll
        for (int j = 0; j < 4; j++)
            acc[i][j] = f32x4{0.f, 0.f, 0.f, 0.f};

    for (int k0 = 0; k0 < K; k0 += 32) {
        __syncthreads();
        load_lds16(ag,         a_lds + (size_t)tid*8);
        load_lds16(ag + row64, a_lds + 2048 + (size_t)tid*8);
        load_lds16(bg,         b_lds + (size_t)tid*8);
        load_lds16(bg + row64, b_lds + 2048 + (size_t)tid*8);
        ag += 32; bg += 32;
        __syncthreads();

        bf16x8 af[4], bf[4];
        #pragma unroll
        for (int i = 0; i < 4; i++) af[i] = *(const bf16x8*)(afr + 16*i*32);
        #pragma unroll
        for (int i = 0; i < 4; i++) bf[i] = *(const bf16x8*)(bfr + 16*i*32);

        #pragma unroll
        for (int mi = 0; mi < 4; mi++)
            #pragma unroll
            for (int ni = 0; ni < 4; ni++)
                acc[mi][ni] = __builtin_amdgcn_mfma_f32_16x16x32_bf16(
                                  af[mi], bf[ni], acc[mi][ni], 0, 0, 0);
    }

    int m0 = m_blk + (wave & 1) * 64;
    int n0 = n_blk + (wave >> 1) * 64;
    #pragma unroll
    for (int ni = 0; ni < 4; ni++) {
        int col = n0 + 16*ni + l15;
        float bv = bias ? bias[col] : 0.f;
        #pragma unroll
        for (int mi = 0; mi < 4; mi++)
            #pragma unroll
            for (int r = 0; r < 4; r++) {
                int row = m0 + 16*mi + quad*4 + r;
                float v = acc[mi][ni][r] + bv;
                if (col < qcols) v *= qscale;
                if (OUTF32) ((float*)Cv)[(size_t)row * Cstride + col] = v;
                else ((unsigned short*)Cv)[(size_t)row * Cstride + col] = f2bf(v);
            }
    }
}

// ---------------- Flash attention, unnormalized-softmax --------------------
// One wave per 32-row Q block (two 16-row strips A/B), 32 keys/iter from one
// interleaved kvpack stream. Each K/V fragment load feeds both strips: 18
// MFMA per iter (8 QK + 8 PV + 2 rowsum) for the same 8 loads -> KV L2
// traffic halves vs 16-row waves. Q carries SCALE*log2e; p = 2^s raw.
__global__ __launch_bounds__(256, 4) void attn_kernel(
    const unsigned short* __restrict__ qkv,    // [MTOT, 3072] (Q cols used)
    const unsigned short* __restrict__ kvpack, // [64 bh][64 t][8 fr][512]
    unsigned short* __restrict__ ctx)          // [MTOT, 1024]
{
    int tid  = threadIdx.x;
    int wave = tid >> 6, lane = tid & 63, quad = lane >> 4, l15 = lane & 15;
    int gw    = blockIdx.x * 4 + wave;
    int bh    = gw >> 6;           // 64 waves of 32 rows per (b,h)
    int strip = gw & 63;
    int b = bh >> 4, h = bh & 15;
    int i0 = strip * 32;

    const unsigned short* qbaseA =
        qkv + (size_t)(b*SEQ + i0 + l15) * QKVN + h*HD + quad*8;
    const unsigned short* qbaseB = qbaseA + (size_t)16 * QKVN;
    bf16x8 qA0 = *(const bf16x8*)(qbaseA);
    bf16x8 qA1 = *(const bf16x8*)(qbaseA + 32);
    bf16x8 qB0 = *(const bf16x8*)(qbaseB);
    bf16x8 qB1 = *(const bf16x8*)(qbaseB + 32);

    // mid-group base: all 8 fragment loads use signed 13-bit imm offsets
    // (-4096..+3072 bytes); one pointer increment of 8192 B per iter.
    const unsigned short* kv =
        kvpack + (size_t)bh * 64 * 4096 + 2048 + (size_t)lane * 8;

    const f32x4 zf = {0.f, 0.f, 0.f, 0.f};
    f32x4 oA[4], oB[4];
    #pragma unroll
    for (int i = 0; i < 4; i++) { oA[i] = zf; oB[i] = zf; }
    f32x4 lA = zf, lB = zf;

    bf16x8 ones;          // bf16 1.0 everywhere — B-operand for rowsum MFMA
    #pragma unroll
    for (int e = 0; e < 8; e++) ones[e] = (short)0x3F80;

    for (int t = 0; t < SEQ/32; t++) {
        bf16x8 k0a = *(const bf16x8*)(kv - 2048);
        bf16x8 k0b = *(const bf16x8*)(kv - 1536);
        bf16x8 k1a = *(const bf16x8*)(kv - 1024);
        bf16x8 k1b = *(const bf16x8*)(kv - 512);
        bf16x8 vf0 = *(const bf16x8*)(kv);
        bf16x8 vf1 = *(const bf16x8*)(kv + 512);
        bf16x8 vf2 = *(const bf16x8*)(kv + 1024);
        bf16x8 vf3 = *(const bf16x8*)(kv + 1536);
        kv += 4096;

        // QK^T for both 16-row strips off the same K fragments
        f32x4 sA0 = __builtin_amdgcn_mfma_f32_16x16x32_bf16(k0a, qA0, zf, 0, 0, 0);
        sA0       = __builtin_amdgcn_mfma_f32_16x16x32_bf16(k0b, qA1, sA0, 0, 0, 0);
        f32x4 sA1 = __builtin_amdgcn_mfma_f32_16x16x32_bf16(k1a, qA0, zf, 0, 0, 0);
        sA1       = __builtin_amdgcn_mfma_f32_16x16x32_bf16(k1b, qA1, sA1, 0, 0, 0);
        f32x4 sB0 = __builtin_amdgcn_mfma_f32_16x16x32_bf16(k0a, qB0, zf, 0, 0, 0);
        sB0       = __builtin_amdgcn_mfma_f32_16x16x32_bf16(k0b, qB1, sB0, 0, 0, 0);
        f32x4 sB1 = __builtin_amdgcn_mfma_f32_16x16x32_bf16(k1a, qB0, zf, 0, 0, 0);
        sB1       = __builtin_amdgcn_mfma_f32_16x16x32_bf16(k1b, qB1, sB1, 0, 0, 0);
        // lane holds S[i=l15][key t*32+quad*8+r] (s*0) and [.. +4+r] (s*1),
        // already scaled by SCALE*log2e via the Q columns.

        union { unsigned int u[4]; bf16x8 v; } pkA, pkB;
        pkA.u[0] = pk2bf(fast_exp2(sA0[0]), fast_exp2(sA0[1]));
        pkA.u[1] = pk2bf(fast_exp2(sA0[2]), fast_exp2(sA0[3]));
        pkA.u[2] = pk2bf(fast_exp2(sA1[0]), fast_exp2(sA1[1]));
        pkA.u[3] = pk2bf(fast_exp2(sA1[2]), fast_exp2(sA1[3]));
        pkB.u[0] = pk2bf(fast_exp2(sB0[0]), fast_exp2(sB0[1]));
        pkB.u[1] = pk2bf(fast_exp2(sB0[2]), fast_exp2(sB0[3]));
        pkB.u[2] = pk2bf(fast_exp2(sB1[0]), fast_exp2(sB1[1]));
        pkB.u[3] = pk2bf(fast_exp2(sB1[2]), fast_exp2(sB1[3]));

        lA    = __builtin_amdgcn_mfma_f32_16x16x32_bf16(pkA.v, ones, lA, 0, 0, 0);
        lB    = __builtin_amdgcn_mfma_f32_16x16x32_bf16(pkB.v, ones, lB, 0, 0, 0);
        oA[0] = __builtin_amdgcn_mfma_f32_16x16x32_bf16(pkA.v, vf0, oA[0], 0, 0, 0);
        oA[1] = __builtin_amdgcn_mfma_f32_16x16x32_bf16(pkA.v, vf1, oA[1], 0, 0, 0);
        oA[2] = __builtin_amdgcn_mfma_f32_16x16x32_bf16(pkA.v, vf2, oA[2], 0, 0, 0);
        oA[3] = __builtin_amdgcn_mfma_f32_16x16x32_bf16(pkA.v, vf3, oA[3], 0, 0, 0);
        oB[0] = __builtin_amdgcn_mfma_f32_16x16x32_bf16(pkB.v, vf0, oB[0], 0, 0, 0);
        oB[1] = __builtin_amdgcn_mfma_f32_16x16x32_bf16(pkB.v, vf1, oB[1], 0, 0, 0);
        oB[2] = __builtin_amdgcn_mfma_f32_16x16x32_bf16(pkB.v, vf2, oB[2], 0, 0, 0);
        oB[3] = __builtin_amdgcn_mfma_f32_16x16x32_bf16(pkB.v, vf3, oB[3], 0, 0, 0);
    }

    // epilogue: l*[r] = full row sum for row quad*4+r (same in every lane)
    #pragma unroll
    for (int r = 0; r < 4; r++) {
        float invA = 1.f / lA[r];
        float invB = 1.f / lB[r];
        int rowA = b*SEQ + i0 + quad*4 + r;
        int rowB = rowA + 16;
        #pragma unroll
        for (int db = 0; db < 4; db++) {
            ctx[(size_t)rowA * CDIM + h*HD + db*16 + l15] = f2bf(oA[db][r] * invA);
            ctx[(size_t)rowB * CDIM + h*HD + db*16 + l15] = f2bf(oB[db][r] * invB);
        }
    }
}

// ---------------------------------------------------------------------------
extern "C" void kernel_launch(void* const* d_in, const int* in_sizes, int n_in,
                              void* d_out, int out_size, void* d_ws, size_t ws_size,
                              hipStream_t stream)
{
    const float* x      = (const float*)d_in[0]; // [8192,1024] fp32
    const float* w_qkv  = (const float*)d_in[1]; // [1024,3072] fp32
    const float* w_proj = (const float*)d_in[2]; // [1024,1024] fp32
    const float* b_proj = (const float*)d_in[3]; // [1024]      fp32
    float* out = (float*)d_out;                  // [8192,1024] fp32

    char* ws = (char*)d_ws;                                      // 104 MiB used
    unsigned short* qkv    = (unsigned short*)(ws);              // [0,48M)
    unsigned short* ctx    = (unsigned short*)(ws + 50331648);   // [48M,64M)
    unsigned short* kvpack = (unsigned short*)(ws + 67108864);   // [64M,96M)
    unsigned short* xb     = (unsigned short*)(ws + 83886080);   // alias: xb dead
                                                                 // before pack_* write
    unsigned short* wqkvT  = (unsigned short*)(ws + 100663296);  // [96M,102M)
    unsigned short* wprojT = (unsigned short*)(ws + 106954752);  // [102M,104M)

    dim3 tb(32, 8);
    transpose_f32_to_bf16<<<dim3(QKVN/32, CDIM/32), tb, 0, stream>>>(
        w_qkv, wqkvT, QKVN, CDIM);
    transpose_f32_to_bf16<<<dim3(CDIM/32, CDIM/32), tb, 0, stream>>>(
        w_proj, wprojT, CDIM, CDIM);

    // xb = bf16(x)
    convert_f32_bf16<<<dim3(MTOT*CDIM/2048), 256, 0, stream>>>(x, xb);

    // qkv = xb @ wqkvT   [8192, 3072] bf16; Q cols pre-scaled by SCALE*log2e
    gemm_lds<false><<<dim3(QKVN/128, MTOT/128), 256, 0, stream>>>(
        xb, wqkvT, qkv, nullptr, CDIM, QKVN, CDIM, QSCALE_LOG2E);

    // pack K and V into fragment-consumption order (overwrites xb region)
    pack_k<<<dim3(64*64), 256, 0, stream>>>(qkv, kvpack);
    pack_v<<<dim3(64*64), 256, 0, stream>>>(qkv, kvpack);

    // flash attention -> ctx [8192, 1024] bf16
    attn_kernel<<<dim3(BN * NH * (SEQ/32) / 4), 256, 0, stream>>>(
        qkv, kvpack, ctx);

    // out = ctx @ wprojT + b_proj   (fp32 out)
    gemm_lds<true><<<dim3(CDIM/128, MTOT/128), 256, 0, stream>>>(
        ctx, wprojT, out, b_proj, CDIM, CDIM, 0, 1.0f);
}

// Round 3
// 298.966 us; speedup vs baseline: 1.1845x; 1.0094x over previous
//
#include <hip/hip_runtime.h>
#include <hip/hip_bf16.h>

// Attention_919123001813 — B=4, N=2048, DIM=1024, H=16, HD=64, SCALE=1/8
// Round 13: attn still KV-BW-bound (22.4 TB/s effective, 65% of L2 ceiling;
// MFMA-busy is a fixed ~31us). Three changes, attn only:
//  (a) 64 Q rows/wave (4 strips): KV L2 traffic halves again -> 1.07 GB.
//      36 MFMA per 32-key iter (16 QK + 16 PV + 4 rowsum) per 8 loads.
//  (b) chunked XCD swizzle (bijective, 512 blocks): all 8 blocks of a bh
//      land on ONE XCD -> per-XCD KV hot set ~8 lockstep streams, fits 4MiB
//      L2 (was ~64 streams = 32MiB -> served from L3 at ~22 TB/s).
//  (c) depth-1 KV register prefetch (named A/B double buffer, rule #20):
//      at 2 waves/SIMD the 8 loads/iter get the full compute phase to land.
// __launch_bounds__(256,2): ~200 VGPR budget, 2 waves/SIMD.

typedef short bf16x8 __attribute__((ext_vector_type(8)));
typedef float f32x4  __attribute__((ext_vector_type(4)));

#define BN   4
#define SEQ  2048
#define CDIM 1024
#define NH   16
#define HD   64
#define QKVN 3072
#define MTOT 8192   // BN*SEQ
// SCALE * log2(e) — folded into Q columns of the QKV GEMM output (fp32).
#define QSCALE_LOG2E 0.18033688011112042f

static __device__ __forceinline__ unsigned short f2bf(float f){
    union { float f; unsigned int i; } v; v.f = f;
    unsigned int r = v.i + 0x7FFFu + ((v.i >> 16) & 1u);   // RNE
    return (unsigned short)(r >> 16);
}

// two fp32 -> one dword of packed bf16 (RNE). gfx950: single v_cvt_pk_bf16_f32.
static __device__ __forceinline__ unsigned int pk2bf(float a, float b){
#if __has_builtin(__builtin_amdgcn_cvt_pk_bf16_f32)
    auto r = __builtin_amdgcn_cvt_pk_bf16_f32(a, b);
    unsigned int u; __builtin_memcpy(&u, &r, 4); return u;
#else
    return (unsigned int)f2bf(a) | ((unsigned int)f2bf(b) << 16);
#endif
}

// raw 2^x (v_exp_f32). Q already carries the SCALE*log2e factor.
static __device__ __forceinline__ float fast_exp2(float x){
#if __has_builtin(__builtin_amdgcn_exp2f)
    return __builtin_amdgcn_exp2f(x);
#else
    return __expf(x * 0.69314718055994531f);
#endif
}

typedef __attribute__((address_space(3))) unsigned int        as3_uint;
typedef const __attribute__((address_space(1))) unsigned int  as1_uint;
static __device__ __forceinline__ void load_lds16(
    const unsigned short* g, unsigned short* l)
{
    __builtin_amdgcn_global_load_lds((as1_uint*)g, (as3_uint*)l, 16, 0, 0);
}

// ---------------- elementwise fp32 -> bf16 (8 elems/thread) ----------------
__global__ __launch_bounds__(256) void convert_f32_bf16(
    const float* __restrict__ in, unsigned short* __restrict__ out)
{
    size_t i = ((size_t)blockIdx.x * 256 + threadIdx.x) * 8;
    f32x4 a = *(const f32x4*)(in + i);
    f32x4 b = *(const f32x4*)(in + i + 4);
    union { unsigned int u[4]; bf16x8 v; } o;
    o.u[0] = pk2bf(a[0], a[1]); o.u[1] = pk2bf(a[2], a[3]);
    o.u[2] = pk2bf(b[0], b[1]); o.u[3] = pk2bf(b[2], b[3]);
    *(bf16x8*)(out + i) = o.v;
}

// ---------------- 32x32 tiled transpose: fp32 in -> bf16 out ---------------
__global__ __launch_bounds__(256) void transpose_f32_to_bf16(
    const float* __restrict__ in, unsigned short* __restrict__ out,
    int in_rs, int out_rs)
{
    __shared__ unsigned short tile[32][33];
    int c0 = blockIdx.x * 32, r0 = blockIdx.y * 32;
    int tx = threadIdx.x, ty = threadIdx.y;
    #pragma unroll
    for (int j = 0; j < 4; j++)
        tile[ty + 8*j][tx] = f2bf(in[(long long)(r0 + ty + 8*j) * in_rs + c0 + tx]);
    __syncthreads();
    #pragma unroll
    for (int j = 0; j < 4; j++)
        out[(long long)(c0 + ty + 8*j) * out_rs + r0 + tx] = tile[tx][ty + 8*j];
}

// ---------------- pack K into fragment order (frags 0..3 of kvpack) --------
__global__ __launch_bounds__(256) void pack_k(
    const unsigned short* __restrict__ qkv, unsigned short* __restrict__ kvpack)
{
    int blk = blockIdx.x;            // bh*64 + t
    int bh = blk >> 6, t = blk & 63;
    int b = bh >> 4, h = bh & 15;
    int tid = threadIdx.x;
    int fr = tid >> 6, l = tid & 63;
    int quad = l >> 4, l15 = l & 15;
    int tb = fr >> 1, d32 = (fr & 1) * 32;
    int row = b*SEQ + t*32 + (l15 >> 2)*8 + (l15 & 3) + 4*tb;
    bf16x8 v = *(const bf16x8*)(qkv + (size_t)row * QKVN + CDIM + h*HD + d32 + quad*8);
    *(bf16x8*)(kvpack + ((size_t)blk*8 + fr)*512 + (size_t)l*8) = v;
}

// ---------------- pack V into fragment order (frags 4..7 of kvpack) --------
__global__ __launch_bounds__(256) void pack_v(
    const unsigned short* __restrict__ qkv, unsigned short* __restrict__ vpack)
{
    __shared__ unsigned short tile[32][66];
    int blk = blockIdx.x;            // bh*64 + t
    int bh = blk >> 6, t = blk & 63;
    int b = bh >> 4, h = bh & 15;
    int tid = threadIdx.x;
    int kk = tid >> 3, dd8 = (tid & 7) * 8;
    bf16x8 v = *(const bf16x8*)(qkv + (size_t)(b*SEQ + t*32 + kk) * QKVN
                                + 2*CDIM + h*HD + dd8);
    #pragma unroll
    for (int e = 0; e < 8; e++) tile[kk][dd8 + e] = v[e];
    __syncthreads();
    int db = tid >> 6, quad = (tid >> 4) & 3, l15 = tid & 15;
    bf16x8 o;
    #pragma unroll
    for (int e = 0; e < 8; e++) o[e] = tile[quad*8 + e][db*16 + l15];
    *(bf16x8*)(vpack + ((size_t)blk*8 + 4 + db)*512 + (size_t)(quad*16 + l15)*8) = o;
}

// ---------------- m97-style LDS-staged GEMM (R8, verified) -----------------
// qcols/qscale: columns [0, qcols) of the output are scaled by qscale in fp32
// BEFORE the bf16 store (used to fold SCALE*log2e into Q at zero precision
// cost). qcols=0 disables.
template<bool OUTF32>
__global__ __launch_bounds__(256) void gemm_lds(
    const unsigned short* __restrict__ A,    // [M,K] bf16
    const unsigned short* __restrict__ BT,   // [N,K] bf16
    void* __restrict__ Cv,                   // [M,Cstride]
    const float* __restrict__ bias,          // [N] or nullptr
    int K, int Cstride, int qcols, float qscale)
{
    __shared__ unsigned short a_lds[128*32];
    __shared__ unsigned short b_lds[128*32];

    int tid  = threadIdx.x;
    int wave = tid >> 6, lane = tid & 63, quad = lane >> 4, l15 = lane & 15;
    int m_blk = blockIdx.y * 128, n_blk = blockIdx.x * 128;

    const unsigned short* ag = A  + (size_t)(m_blk + (tid >> 2)) * K + (tid & 3)*8;
    const unsigned short* bg = BT + (size_t)(n_blk + (tid >> 2)) * K + (tid & 3)*8;
    const size_t row64 = (size_t)64 * K;

    unsigned short* afr = a_lds + ((wave & 1)*64 + l15)*32 + quad*8;
    unsigned short* bfr = b_lds + ((wave >> 1)*64 + l15)*32 + quad*8;

    f32x4 acc[4][4];
    #pragma unroll
    for (int i = 0; i < 4; i++)
        #pragma unroll
        for (int j = 0; j < 4; j++)
            acc[i][j] = f32x4{0.f, 0.f, 0.f, 0.f};

    for (int k0 = 0; k0 < K; k0 += 32) {
        __syncthreads();
        load_lds16(ag,         a_lds + (size_t)tid*8);
        load_lds16(ag + row64, a_lds + 2048 + (size_t)tid*8);
        load_lds16(bg,         b_lds + (size_t)tid*8);
        load_lds16(bg + row64, b_lds + 2048 + (size_t)tid*8);
        ag += 32; bg += 32;
        __syncthreads();

        bf16x8 af[4], bf[4];
        #pragma unroll
        for (int i = 0; i < 4; i++) af[i] = *(const bf16x8*)(afr + 16*i*32);
        #pragma unroll
        for (int i = 0; i < 4; i++) bf[i] = *(const bf16x8*)(bfr + 16*i*32);

        #pragma unroll
        for (int mi = 0; mi < 4; mi++)
            #pragma unroll
            for (int ni = 0; ni < 4; ni++)
                acc[mi][ni] = __builtin_amdgcn_mfma_f32_16x16x32_bf16(
                                  af[mi], bf[ni], acc[mi][ni], 0, 0, 0);
    }

    int m0 = m_blk + (wave & 1) * 64;
    int n0 = n_blk + (wave >> 1) * 64;
    #pragma unroll
    for (int ni = 0; ni < 4; ni++) {
        int col = n0 + 16*ni + l15;
        float bv = bias ? bias[col] : 0.f;
        #pragma unroll
        for (int mi = 0; mi < 4; mi++)
            #pragma unroll
            for (int r = 0; r < 4; r++) {
                int row = m0 + 16*mi + quad*4 + r;
                float v = acc[mi][ni][r] + bv;
                if (col < qcols) v *= qscale;
                if (OUTF32) ((float*)Cv)[(size_t)row * Cstride + col] = v;
                else ((unsigned short*)Cv)[(size_t)row * Cstride + col] = f2bf(v);
            }
    }
}

// ---------------- Flash attention, unnormalized-softmax --------------------
// One wave per 64-row Q block (4 strips), 32 keys/iter from one interleaved
// kvpack stream. Each KV fragment load feeds 4 strips: 36 MFMA per iter
// (16 QK + 16 PV + 4 rowsum) per 8 loads. Chunked XCD swizzle keeps each
// bh's 8 blocks on one XCD (L2-resident lockstep streams). Depth-1 KV
// register prefetch (A/B named buffers). Q carries SCALE*log2e; p = 2^s.

#define LOADKV(K0A,K0B,K1A,K1B,V0,V1,V2,V3, PTR)        \
    K0A = *(const bf16x8*)((PTR) - 2048);               \
    K0B = *(const bf16x8*)((PTR) - 1536);               \
    K1A = *(const bf16x8*)((PTR) - 1024);               \
    K1B = *(const bf16x8*)((PTR) - 512);                \
    V0  = *(const bf16x8*)((PTR));                      \
    V1  = *(const bf16x8*)((PTR) + 512);                \
    V2  = *(const bf16x8*)((PTR) + 1024);               \
    V3  = *(const bf16x8*)((PTR) + 1536);

#define ATTN_STEP(K0A,K0B,K1A,K1B,V0,V1,V2,V3)                                        \
    _Pragma("unroll")                                                                  \
    for (int s = 0; s < 4; ++s) {                                                      \
        f32x4 s0 = __builtin_amdgcn_mfma_f32_16x16x32_bf16(K0A, q0[s], zf, 0, 0, 0);   \
        s0       = __builtin_amdgcn_mfma_f32_16x16x32_bf16(K0B, q1[s], s0, 0, 0, 0);   \
        f32x4 s1 = __builtin_amdgcn_mfma_f32_16x16x32_bf16(K1A, q0[s], zf, 0, 0, 0);   \
        s1       = __builtin_amdgcn_mfma_f32_16x16x32_bf16(K1B, q1[s], s1, 0, 0, 0);   \
        union { unsigned int u[4]; bf16x8 v; } pk;                                     \
        pk.u[0] = pk2bf(fast_exp2(s0[0]), fast_exp2(s0[1]));                           \
        pk.u[1] = pk2bf(fast_exp2(s0[2]), fast_exp2(s0[3]));                           \
        pk.u[2] = pk2bf(fast_exp2(s1[0]), fast_exp2(s1[1]));                           \
        pk.u[3] = pk2bf(fast_exp2(s1[2]), fast_exp2(s1[3]));                           \
        lacc[s] = __builtin_amdgcn_mfma_f32_16x16x32_bf16(pk.v, ones, lacc[s], 0,0,0); \
        o[s][0] = __builtin_amdgcn_mfma_f32_16x16x32_bf16(pk.v, V0, o[s][0], 0, 0, 0); \
        o[s][1] = __builtin_amdgcn_mfma_f32_16x16x32_bf16(pk.v, V1, o[s][1], 0, 0, 0); \
        o[s][2] = __builtin_amdgcn_mfma_f32_16x16x32_bf16(pk.v, V2, o[s][2], 0, 0, 0); \
        o[s][3] = __builtin_amdgcn_mfma_f32_16x16x32_bf16(pk.v, V3, o[s][3], 0, 0, 0); \
    }

__global__ __launch_bounds__(256, 2) void attn_kernel(
    const unsigned short* __restrict__ qkv,    // [MTOT, 3072] (Q cols used)
    const unsigned short* __restrict__ kvpack, // [64 bh][64 t][8 fr][512]
    unsigned short* __restrict__ ctx)          // [MTOT, 1024]
{
    int tid  = threadIdx.x;
    int wave = tid >> 6, lane = tid & 63, quad = lane >> 4, l15 = lane & 15;
    // chunked XCD swizzle: 512 blocks, HW round-robins blockIdx%8 across
    // XCDs -> logical block (p&7)*64 + (p>>3) puts each bh's 8 blocks on
    // ONE XCD (bijective since 512 % 8 == 0).
    int p  = blockIdx.x;
    int L  = (p & 7) * 64 + (p >> 3);
    int gw    = L * 4 + wave;
    int bh    = gw >> 5;           // 32 waves of 64 rows per (b,h)
    int strip = gw & 31;
    int b = bh >> 4, h = bh & 15;
    int i0 = strip * 64;

    bf16x8 q0[4], q1[4];
    #pragma unroll
    for (int s = 0; s < 4; ++s) {
        const unsigned short* qb =
            qkv + (size_t)(b*SEQ + i0 + s*16 + l15) * QKVN + h*HD + quad*8;
        q0[s] = *(const bf16x8*)(qb);
        q1[s] = *(const bf16x8*)(qb + 32);
    }

    // mid-group base: all 8 fragment loads use signed 13-bit imm offsets
    const unsigned short* kv =
        kvpack + (size_t)bh * 64 * 4096 + 2048 + (size_t)lane * 8;

    const f32x4 zf = {0.f, 0.f, 0.f, 0.f};
    f32x4 o[4][4];
    #pragma unroll
    for (int s = 0; s < 4; ++s)
        #pragma unroll
        for (int i = 0; i < 4; i++) o[s][i] = zf;
    f32x4 lacc[4];
    #pragma unroll
    for (int s = 0; s < 4; ++s) lacc[s] = zf;

    bf16x8 ones;          // bf16 1.0 everywhere — B-operand for rowsum MFMA
    #pragma unroll
    for (int e = 0; e < 8; e++) ones[e] = (short)0x3F80;

    // depth-1 prefetch: A holds iter 2*t2, B holds iter 2*t2+1
    bf16x8 Ak0a, Ak0b, Ak1a, Ak1b, Av0, Av1, Av2, Av3;
    bf16x8 Bk0a, Bk0b, Bk1a, Bk1b, Bv0, Bv1, Bv2, Bv3;

    LOADKV(Ak0a, Ak0b, Ak1a, Ak1b, Av0, Av1, Av2, Av3, kv);
    const unsigned short* kvn = kv + 4096;

    for (int t2 = 0; t2 < 32; ++t2) {
        LOADKV(Bk0a, Bk0b, Bk1a, Bk1b, Bv0, Bv1, Bv2, Bv3, kvn);
        ATTN_STEP(Ak0a, Ak0b, Ak1a, Ak1b, Av0, Av1, Av2, Av3);
        if (t2 < 31) {
            LOADKV(Ak0a, Ak0b, Ak1a, Ak1b, Av0, Av1, Av2, Av3, kvn + 4096);
        }
        kvn += 8192;
        ATTN_STEP(Bk0a, Bk0b, Bk1a, Bk1b, Bv0, Bv1, Bv2, Bv3);
    }

    // epilogue: lacc[s][r] = full row sum for row s*16+quad*4+r (all lanes)
    #pragma unroll
    for (int s = 0; s < 4; ++s)
        #pragma unroll
        for (int r = 0; r < 4; r++) {
            float inv = 1.f / lacc[s][r];
            int row = b*SEQ + i0 + s*16 + quad*4 + r;
            #pragma unroll
            for (int db = 0; db < 4; db++)
                ctx[(size_t)row * CDIM + h*HD + db*16 + l15] =
                    f2bf(o[s][db][r] * inv);
        }
}

// ---------------------------------------------------------------------------
extern "C" void kernel_launch(void* const* d_in, const int* in_sizes, int n_in,
                              void* d_out, int out_size, void* d_ws, size_t ws_size,
                              hipStream_t stream)
{
    const float* x      = (const float*)d_in[0]; // [8192,1024] fp32
    const float* w_qkv  = (const float*)d_in[1]; // [1024,3072] fp32
    const float* w_proj = (const float*)d_in[2]; // [1024,1024] fp32
    const float* b_proj = (const float*)d_in[3]; // [1024]      fp32
    float* out = (float*)d_out;                  // [8192,1024] fp32

    char* ws = (char*)d_ws;                                      // 104 MiB used
    unsigned short* qkv    = (unsigned short*)(ws);              // [0,48M)
    unsigned short* ctx    = (unsigned short*)(ws + 50331648);   // [48M,64M)
    unsigned short* kvpack = (unsigned short*)(ws + 67108864);   // [64M,96M)
    unsigned short* xb     = (unsigned short*)(ws + 83886080);   // alias: xb dead
                                                                 // before pack_* write
    unsigned short* wqkvT  = (unsigned short*)(ws + 100663296);  // [96M,102M)
    unsigned short* wprojT = (unsigned short*)(ws + 106954752);  // [102M,104M)

    dim3 tb(32, 8);
    transpose_f32_to_bf16<<<dim3(QKVN/32, CDIM/32), tb, 0, stream>>>(
        w_qkv, wqkvT, QKVN, CDIM);
    transpose_f32_to_bf16<<<dim3(CDIM/32, CDIM/32), tb, 0, stream>>>(
        w_proj, wprojT, CDIM, CDIM);

    // xb = bf16(x)
    convert_f32_bf16<<<dim3(MTOT*CDIM/2048), 256, 0, stream>>>(x, xb);

    // qkv = xb @ wqkvT   [8192, 3072] bf16; Q cols pre-scaled by SCALE*log2e
    gemm_lds<false><<<dim3(QKVN/128, MTOT/128), 256, 0, stream>>>(
        xb, wqkvT, qkv, nullptr, CDIM, QKVN, CDIM, QSCALE_LOG2E);

    // pack K and V into fragment-consumption order (overwrites xb region)
    pack_k<<<dim3(64*64), 256, 0, stream>>>(qkv, kvpack);
    pack_v<<<dim3(64*64), 256, 0, stream>>>(qkv, kvpack);

    // flash attention -> ctx [8192, 1024] bf16
    attn_kernel<<<dim3(BN * NH * (SEQ/64) / 4), 256, 0, stream>>>(
        qkv, kvpack, ctx);

    // out = ctx @ wprojT + b_proj   (fp32 out)
    gemm_lds<true><<<dim3(CDIM/128, MTOT/128), 256, 0, stream>>>(
        ctx, wprojT, out, b_proj, CDIM, CDIM, 0, 1.0f);
}

// Round 4
// 297.801 us; speedup vs baseline: 1.1891x; 1.0039x over previous
//
#include <hip/hip_runtime.h>
#include <hip/hip_bf16.h>

// Attention_919123001813 — B=4, N=2048, DIM=1024, H=16, HD=64, SCALE=1/8
// Round 14: R13 showed attn is LATENCY-bound, not BW-bound (FETCH dropped
// 6x with the XCD swizzle but dur unchanged; occupancy 18% = 2 waves/SIMD,
// MfmaUtil 35% = the 31us MFMA floor / 93us, ~45us pure stall).
// Fix: block-cooperative KV staging through LDS.
//  - 4 waves/block x 32 Q rows = 128 rows/block, 1024 blocks (4/CU exactly).
//  - each 8KiB 32-key KV tile staged ONCE per block via global_load_lds(16B)
//    (kvpack is lane-linear = exactly the layout global_load_lds needs),
//    double-buffered, 2-phase schedule; all 4 waves consume it.
//  - per-wave regs ~110 -> __launch_bounds__(256,4) = 4 waves/SIMD; 4
//    independent blocks/CU overlap each other's barrier stalls.
//  - KV L2 traffic 537MB (~16us at L2 ceiling, not binding); ds_read_b128
//    lane-contiguous = conflict-free.
//  - keep chunked XCD swizzle: 8 bh per XCD = 4MiB = L2-resident.

typedef short bf16x8 __attribute__((ext_vector_type(8)));
typedef float f32x4  __attribute__((ext_vector_type(4)));

#define BN   4
#define SEQ  2048
#define CDIM 1024
#define NH   16
#define HD   64
#define QKVN 3072
#define MTOT 8192   // BN*SEQ
// SCALE * log2(e) — folded into Q columns of the QKV GEMM output (fp32).
#define QSCALE_LOG2E 0.18033688011112042f

static __device__ __forceinline__ unsigned short f2bf(float f){
    union { float f; unsigned int i; } v; v.f = f;
    unsigned int r = v.i + 0x7FFFu + ((v.i >> 16) & 1u);   // RNE
    return (unsigned short)(r >> 16);
}

// two fp32 -> one dword of packed bf16 (RNE). gfx950: single v_cvt_pk_bf16_f32.
static __device__ __forceinline__ unsigned int pk2bf(float a, float b){
#if __has_builtin(__builtin_amdgcn_cvt_pk_bf16_f32)
    auto r = __builtin_amdgcn_cvt_pk_bf16_f32(a, b);
    unsigned int u; __builtin_memcpy(&u, &r, 4); return u;
#else
    return (unsigned int)f2bf(a) | ((unsigned int)f2bf(b) << 16);
#endif
}

// raw 2^x (v_exp_f32). Q already carries the SCALE*log2e factor.
static __device__ __forceinline__ float fast_exp2(float x){
#if __has_builtin(__builtin_amdgcn_exp2f)
    return __builtin_amdgcn_exp2f(x);
#else
    return __expf(x * 0.69314718055994531f);
#endif
}

typedef __attribute__((address_space(3))) unsigned int        as3_uint;
typedef const __attribute__((address_space(1))) unsigned int  as1_uint;
static __device__ __forceinline__ void load_lds16(
    const unsigned short* g, unsigned short* l)
{
    __builtin_amdgcn_global_load_lds((as1_uint*)g, (as3_uint*)l, 16, 0, 0);
}

// ---------------- elementwise fp32 -> bf16 (8 elems/thread) ----------------
__global__ __launch_bounds__(256) void convert_f32_bf16(
    const float* __restrict__ in, unsigned short* __restrict__ out)
{
    size_t i = ((size_t)blockIdx.x * 256 + threadIdx.x) * 8;
    f32x4 a = *(const f32x4*)(in + i);
    f32x4 b = *(const f32x4*)(in + i + 4);
    union { unsigned int u[4]; bf16x8 v; } o;
    o.u[0] = pk2bf(a[0], a[1]); o.u[1] = pk2bf(a[2], a[3]);
    o.u[2] = pk2bf(b[0], b[1]); o.u[3] = pk2bf(b[2], b[3]);
    *(bf16x8*)(out + i) = o.v;
}

// ---------------- 32x32 tiled transpose: fp32 in -> bf16 out ---------------
__global__ __launch_bounds__(256) void transpose_f32_to_bf16(
    const float* __restrict__ in, unsigned short* __restrict__ out,
    int in_rs, int out_rs)
{
    __shared__ unsigned short tile[32][33];
    int c0 = blockIdx.x * 32, r0 = blockIdx.y * 32;
    int tx = threadIdx.x, ty = threadIdx.y;
    #pragma unroll
    for (int j = 0; j < 4; j++)
        tile[ty + 8*j][tx] = f2bf(in[(long long)(r0 + ty + 8*j) * in_rs + c0 + tx]);
    __syncthreads();
    #pragma unroll
    for (int j = 0; j < 4; j++)
        out[(long long)(c0 + ty + 8*j) * out_rs + r0 + tx] = tile[tx][ty + 8*j];
}

// ---------------- pack K into fragment order (frags 0..3 of kvpack) --------
__global__ __launch_bounds__(256) void pack_k(
    const unsigned short* __restrict__ qkv, unsigned short* __restrict__ kvpack)
{
    int blk = blockIdx.x;            // bh*64 + t
    int bh = blk >> 6, t = blk & 63;
    int b = bh >> 4, h = bh & 15;
    int tid = threadIdx.x;
    int fr = tid >> 6, l = tid & 63;
    int quad = l >> 4, l15 = l & 15;
    int tb = fr >> 1, d32 = (fr & 1) * 32;
    int row = b*SEQ + t*32 + (l15 >> 2)*8 + (l15 & 3) + 4*tb;
    bf16x8 v = *(const bf16x8*)(qkv + (size_t)row * QKVN + CDIM + h*HD + d32 + quad*8);
    *(bf16x8*)(kvpack + ((size_t)blk*8 + fr)*512 + (size_t)l*8) = v;
}

// ---------------- pack V into fragment order (frags 4..7 of kvpack) --------
__global__ __launch_bounds__(256) void pack_v(
    const unsigned short* __restrict__ qkv, unsigned short* __restrict__ vpack)
{
    __shared__ unsigned short tile[32][66];
    int blk = blockIdx.x;            // bh*64 + t
    int bh = blk >> 6, t = blk & 63;
    int b = bh >> 4, h = bh & 15;
    int tid = threadIdx.x;
    int kk = tid >> 3, dd8 = (tid & 7) * 8;
    bf16x8 v = *(const bf16x8*)(qkv + (size_t)(b*SEQ + t*32 + kk) * QKVN
                                + 2*CDIM + h*HD + dd8);
    #pragma unroll
    for (int e = 0; e < 8; e++) tile[kk][dd8 + e] = v[e];
    __syncthreads();
    int db = tid >> 6, quad = (tid >> 4) & 3, l15 = tid & 15;
    bf16x8 o;
    #pragma unroll
    for (int e = 0; e < 8; e++) o[e] = tile[quad*8 + e][db*16 + l15];
    *(bf16x8*)(vpack + ((size_t)blk*8 + 4 + db)*512 + (size_t)(quad*16 + l15)*8) = o;
}

// ---------------- m97-style LDS-staged GEMM (R8, verified) -----------------
// qcols/qscale: columns [0, qcols) of the output are scaled by qscale in fp32
// BEFORE the bf16 store (used to fold SCALE*log2e into Q at zero precision
// cost). qcols=0 disables.
template<bool OUTF32>
__global__ __launch_bounds__(256) void gemm_lds(
    const unsigned short* __restrict__ A,    // [M,K] bf16
    const unsigned short* __restrict__ BT,   // [N,K] bf16
    void* __restrict__ Cv,                   // [M,Cstride]
    const float* __restrict__ bias,          // [N] or nullptr
    int K, int Cstride, int qcols, float qscale)
{
    __shared__ unsigned short a_lds[128*32];
    __shared__ unsigned short b_lds[128*32];

    int tid  = threadIdx.x;
    int wave = tid >> 6, lane = tid & 63, quad = lane >> 4, l15 = lane & 15;
    int m_blk = blockIdx.y * 128, n_blk = blockIdx.x * 128;

    const unsigned short* ag = A  + (size_t)(m_blk + (tid >> 2)) * K + (tid & 3)*8;
    const unsigned short* bg = BT + (size_t)(n_blk + (tid >> 2)) * K + (tid & 3)*8;
    const size_t row64 = (size_t)64 * K;

    unsigned short* afr = a_lds + ((wave & 1)*64 + l15)*32 + quad*8;
    unsigned short* bfr = b_lds + ((wave >> 1)*64 + l15)*32 + quad*8;

    f32x4 acc[4][4];
    #pragma unroll
    for (int i = 0; i < 4; i++)
        #pragma unroll
        for (int j = 0; j < 4; j++)
            acc[i][j] = f32x4{0.f, 0.f, 0.f, 0.f};

    for (int k0 = 0; k0 < K; k0 += 32) {
        __syncthreads();
        load_lds16(ag,         a_lds + (size_t)tid*8);
        load_lds16(ag + row64, a_lds + 2048 + (size_t)tid*8);
        load_lds16(bg,         b_lds + (size_t)tid*8);
        load_lds16(bg + row64, b_lds + 2048 + (size_t)tid*8);
        ag += 32; bg += 32;
        __syncthreads();

        bf16x8 af[4], bf[4];
        #pragma unroll
        for (int i = 0; i < 4; i++) af[i] = *(const bf16x8*)(afr + 16*i*32);
        #pragma unroll
        for (int i = 0; i < 4; i++) bf[i] = *(const bf16x8*)(bfr + 16*i*32);

        #pragma unroll
        for (int mi = 0; mi < 4; mi++)
            #pragma unroll
            for (int ni = 0; ni < 4; ni++)
                acc[mi][ni] = __builtin_amdgcn_mfma_f32_16x16x32_bf16(
                                  af[mi], bf[ni], acc[mi][ni], 0, 0, 0);
    }

    int m0 = m_blk + (wave & 1) * 64;
    int n0 = n_blk + (wave >> 1) * 64;
    #pragma unroll
    for (int ni = 0; ni < 4; ni++) {
        int col = n0 + 16*ni + l15;
        float bv = bias ? bias[col] : 0.f;
        #pragma unroll
        for (int mi = 0; mi < 4; mi++)
            #pragma unroll
            for (int r = 0; r < 4; r++) {
                int row = m0 + 16*mi + quad*4 + r;
                float v = acc[mi][ni][r] + bv;
                if (col < qcols) v *= qscale;
                if (OUTF32) ((float*)Cv)[(size_t)row * Cstride + col] = v;
                else ((unsigned short*)Cv)[(size_t)row * Cstride + col] = f2bf(v);
            }
    }
}

// ---------------- Flash attention, unnormalized-softmax --------------------
// 4 waves/block, 32 Q rows each (2 strips A/B). KV staged per 32-key tile
// (8KiB) into LDS once per block via global_load_lds, double-buffered,
// 2-phase. 18 MFMA per tile per wave (8 QK + 8 PV + 2 rowsum). Q carries
// SCALE*log2e; p = 2^s.

__global__ __launch_bounds__(256, 4) void attn_kernel(
    const unsigned short* __restrict__ qkv,    // [MTOT, 3072] (Q cols used)
    const unsigned short* __restrict__ kvpack, // [64 bh][64 t][8 fr][512]
    unsigned short* __restrict__ ctx)          // [MTOT, 1024]
{
    __shared__ unsigned short kvtile[2][4096];  // 2 x 8 KiB double buffer

    int tid  = threadIdx.x;
    int wave = tid >> 6, lane = tid & 63, quad = lane >> 4, l15 = lane & 15;
    // chunked XCD swizzle: 1024 blocks, HW round-robins blockIdx%8 across
    // XCDs -> logical block (p&7)*128 + (p>>3) puts each bh's 16 blocks on
    // ONE XCD (bijective since 1024 % 8 == 0). 8 bh/XCD = 4 MiB KV = L2.
    int p  = blockIdx.x;
    int L  = (p & 7) * 128 + (p >> 3);
    int bh = L >> 4;                 // 16 blocks per (b,h)
    int rb = L & 15;
    int b = bh >> 4, h = bh & 15;
    int i0 = rb * 128 + wave * 32;   // this wave's 32 rows (2 strips)

    const unsigned short* qbA =
        qkv + (size_t)(b*SEQ + i0 + l15) * QKVN + h*HD + quad*8;
    const unsigned short* qbB = qbA + (size_t)16 * QKVN;
    bf16x8 qA0 = *(const bf16x8*)(qbA);
    bf16x8 qA1 = *(const bf16x8*)(qbA + 32);
    bf16x8 qB0 = *(const bf16x8*)(qbB);
    bf16x8 qB1 = *(const bf16x8*)(qbB + 32);

    // flat KV stream for this bh: 64 tiles x 4096 shorts, lane-linear.
    const unsigned short* kvg = kvpack + (size_t)bh * 64 * 4096;

#define STAGE(BUF, T) do {                                                     \
        load_lds16(kvg + (size_t)(T)*4096 + tid*8,        &kvtile[BUF][tid*8]);\
        load_lds16(kvg + (size_t)(T)*4096 + 2048 + tid*8,                      \
                   &kvtile[BUF][2048 + tid*8]);                                \
    } while (0)

    const unsigned short* lds0 = &kvtile[0][lane*8];
    const unsigned short* lds1 = &kvtile[1][lane*8];

    const f32x4 zf = {0.f, 0.f, 0.f, 0.f};
    f32x4 oA0 = zf, oA1 = zf, oA2 = zf, oA3 = zf;
    f32x4 oB0 = zf, oB1 = zf, oB2 = zf, oB3 = zf;
    f32x4 lA = zf, lB = zf;

    bf16x8 ones;          // bf16 1.0 everywhere — B-operand for rowsum MFMA
    #pragma unroll
    for (int e = 0; e < 8; e++) ones[e] = (short)0x3F80;

#define ATTN_TILE(LK)                                                              \
    {                                                                              \
        bf16x8 k0a = *(const bf16x8*)((LK));                                       \
        bf16x8 k0b = *(const bf16x8*)((LK) + 512);                                 \
        bf16x8 k1a = *(const bf16x8*)((LK) + 1024);                                \
        bf16x8 k1b = *(const bf16x8*)((LK) + 1536);                                \
        bf16x8 v0  = *(const bf16x8*)((LK) + 2048);                                \
        bf16x8 v1  = *(const bf16x8*)((LK) + 2560);                                \
        bf16x8 v2  = *(const bf16x8*)((LK) + 3072);                                \
        bf16x8 v3  = *(const bf16x8*)((LK) + 3584);                                \
        f32x4 sA0 = __builtin_amdgcn_mfma_f32_16x16x32_bf16(k0a, qA0, zf, 0,0,0);  \
        sA0 = __builtin_amdgcn_mfma_f32_16x16x32_bf16(k0b, qA1, sA0, 0,0,0);       \
        f32x4 sA1 = __builtin_amdgcn_mfma_f32_16x16x32_bf16(k1a, qA0, zf, 0,0,0);  \
        sA1 = __builtin_amdgcn_mfma_f32_16x16x32_bf16(k1b, qA1, sA1, 0,0,0);       \
        f32x4 sB0 = __builtin_amdgcn_mfma_f32_16x16x32_bf16(k0a, qB0, zf, 0,0,0);  \
        sB0 = __builtin_amdgcn_mfma_f32_16x16x32_bf16(k0b, qB1, sB0, 0,0,0);       \
        f32x4 sB1 = __builtin_amdgcn_mfma_f32_16x16x32_bf16(k1a, qB0, zf, 0,0,0);  \
        sB1 = __builtin_amdgcn_mfma_f32_16x16x32_bf16(k1b, qB1, sB1, 0,0,0);       \
        union { unsigned int u[4]; bf16x8 v; } pkA, pkB;                           \
        pkA.u[0] = pk2bf(fast_exp2(sA0[0]), fast_exp2(sA0[1]));                    \
        pkA.u[1] = pk2bf(fast_exp2(sA0[2]), fast_exp2(sA0[3]));                    \
        pkA.u[2] = pk2bf(fast_exp2(sA1[0]), fast_exp2(sA1[1]));                    \
        pkA.u[3] = pk2bf(fast_exp2(sA1[2]), fast_exp2(sA1[3]));                    \
        pkB.u[0] = pk2bf(fast_exp2(sB0[0]), fast_exp2(sB0[1]));                    \
        pkB.u[1] = pk2bf(fast_exp2(sB0[2]), fast_exp2(sB0[3]));                    \
        pkB.u[2] = pk2bf(fast_exp2(sB1[0]), fast_exp2(sB1[1]));                    \
        pkB.u[3] = pk2bf(fast_exp2(sB1[2]), fast_exp2(sB1[3]));                    \
        lA  = __builtin_amdgcn_mfma_f32_16x16x32_bf16(pkA.v, ones, lA, 0,0,0);     \
        lB  = __builtin_amdgcn_mfma_f32_16x16x32_bf16(pkB.v, ones, lB, 0,0,0);     \
        oA0 = __builtin_amdgcn_mfma_f32_16x16x32_bf16(pkA.v, v0, oA0, 0,0,0);      \
        oA1 = __builtin_amdgcn_mfma_f32_16x16x32_bf16(pkA.v, v1, oA1, 0,0,0);      \
        oA2 = __builtin_amdgcn_mfma_f32_16x16x32_bf16(pkA.v, v2, oA2, 0,0,0);      \
        oA3 = __builtin_amdgcn_mfma_f32_16x16x32_bf16(pkA.v, v3, oA3, 0,0,0);      \
        oB0 = __builtin_amdgcn_mfma_f32_16x16x32_bf16(pkB.v, v0, oB0, 0,0,0);      \
        oB1 = __builtin_amdgcn_mfma_f32_16x16x32_bf16(pkB.v, v1, oB1, 0,0,0);      \
        oB2 = __builtin_amdgcn_mfma_f32_16x16x32_bf16(pkB.v, v2, oB2, 0,0,0);      \
        oB3 = __builtin_amdgcn_mfma_f32_16x16x32_bf16(pkB.v, v3, oB3, 0,0,0);      \
    }

    STAGE(0, 0);
    __syncthreads();                   // compiler drains vmcnt before barrier

    for (int t = 0; t < 64; t += 2) {
        STAGE(1, t + 1);               // issue early: lands under compute
        ATTN_TILE(lds0);               // tile t
        __syncthreads();               // buf1 ready, buf0 free
        if (t + 2 < 64) STAGE(0, t + 2);
        ATTN_TILE(lds1);               // tile t+1
        __syncthreads();               // buf0 ready, buf1 free
    }

    // epilogue: l*[r] = full row sum for row quad*4+r (same in every lane)
    #pragma unroll
    for (int r = 0; r < 4; r++) {
        float invA = 1.f / lA[r];
        float invB = 1.f / lB[r];
        int rowA = b*SEQ + i0 + quad*4 + r;
        size_t baseA = (size_t)rowA * CDIM + h*HD + l15;
        size_t baseB = baseA + (size_t)16 * CDIM;
        ctx[baseA]      = f2bf(oA0[r] * invA);
        ctx[baseA + 16] = f2bf(oA1[r] * invA);
        ctx[baseA + 32] = f2bf(oA2[r] * invA);
        ctx[baseA + 48] = f2bf(oA3[r] * invA);
        ctx[baseB]      = f2bf(oB0[r] * invB);
        ctx[baseB + 16] = f2bf(oB1[r] * invB);
        ctx[baseB + 32] = f2bf(oB2[r] * invB);
        ctx[baseB + 48] = f2bf(oB3[r] * invB);
    }
#undef STAGE
#undef ATTN_TILE
}

// ---------------------------------------------------------------------------
extern "C" void kernel_launch(void* const* d_in, const int* in_sizes, int n_in,
                              void* d_out, int out_size, void* d_ws, size_t ws_size,
                              hipStream_t stream)
{
    const float* x      = (const float*)d_in[0]; // [8192,1024] fp32
    const float* w_qkv  = (const float*)d_in[1]; // [1024,3072] fp32
    const float* w_proj = (const float*)d_in[2]; // [1024,1024] fp32
    const float* b_proj = (const float*)d_in[3]; // [1024]      fp32
    float* out = (float*)d_out;                  // [8192,1024] fp32

    char* ws = (char*)d_ws;                                      // 104 MiB used
    unsigned short* qkv    = (unsigned short*)(ws);              // [0,48M)
    unsigned short* ctx    = (unsigned short*)(ws + 50331648);   // [48M,64M)
    unsigned short* kvpack = (unsigned short*)(ws + 67108864);   // [64M,96M)
    unsigned short* xb     = (unsigned short*)(ws + 83886080);   // alias: xb dead
                                                                 // before pack_* write
    unsigned short* wqkvT  = (unsigned short*)(ws + 100663296);  // [96M,102M)
    unsigned short* wprojT = (unsigned short*)(ws + 106954752);  // [102M,104M)

    dim3 tb(32, 8);
    transpose_f32_to_bf16<<<dim3(QKVN/32, CDIM/32), tb, 0, stream>>>(
        w_qkv, wqkvT, QKVN, CDIM);
    transpose_f32_to_bf16<<<dim3(CDIM/32, CDIM/32), tb, 0, stream>>>(
        w_proj, wprojT, CDIM, CDIM);

    // xb = bf16(x)
    convert_f32_bf16<<<dim3(MTOT*CDIM/2048), 256, 0, stream>>>(x, xb);

    // qkv = xb @ wqkvT   [8192, 3072] bf16; Q cols pre-scaled by SCALE*log2e
    gemm_lds<false><<<dim3(QKVN/128, MTOT/128), 256, 0, stream>>>(
        xb, wqkvT, qkv, nullptr, CDIM, QKVN, CDIM, QSCALE_LOG2E);

    // pack K and V into fragment-consumption order (overwrites xb region)
    pack_k<<<dim3(64*64), 256, 0, stream>>>(qkv, kvpack);
    pack_v<<<dim3(64*64), 256, 0, stream>>>(qkv, kvpack);

    // flash attention -> ctx [8192, 1024] bf16
    attn_kernel<<<dim3(BN * NH * (SEQ/128)), 256, 0, stream>>>(
        qkv, kvpack, ctx);

    // out = ctx @ wprojT + b_proj   (fp32 out)
    gemm_lds<true><<<dim3(CDIM/128, MTOT/128), 256, 0, stream>>>(
        ctx, wprojT, out, b_proj, CDIM, CDIM, 0, 1.0f);
}

// Round 5
// 297.226 us; speedup vs baseline: 1.1914x; 1.0019x over previous
//
#include <hip/hip_runtime.h>
#include <hip/hip_bf16.h>

// Attention_919123001813 — B=4, N=2048, DIM=1024, H=16, HD=64, SCALE=1/8
// Round 15: R14 still ~90us: MfmaUtil 36% = MFMA-floor/dur, true VALU ~18%,
// nothing saturated -> the __syncthreads vmcnt(0) drain stalls every phase
// (the guide's known 2-phase structural stall). Fix = T4 counted vmcnt:
//  - 4-buffer LDS ring (32 KiB), prefetch distance 3.
//  - raw s_barrier + inline-asm s_waitcnt vmcnt(4) (tail 2,0) -> 6
//    global_load_lds stay in flight ACROSS barriers; each STAGE gets ~3
//    tiles of compute to land (vs ~1 before).
//  - safety: vmcnt retires in-order so vmcnt(4) == tile-t loads done; barrier
//    after the wait publishes all waves' quarters; buffer (t+3)&3 == t-1 is
//    dead (all ds_reads of t-1 consumed before barrier t via compiler
//    lgkmcnt waits); sched_barrier(0)+memory clobbers pin ordering; Q-loads
//    drained (vmcnt(0)) before prologue STAGEs so loop counting is exact.

typedef short bf16x8 __attribute__((ext_vector_type(8)));
typedef float f32x4  __attribute__((ext_vector_type(4)));

#define BN   4
#define SEQ  2048
#define CDIM 1024
#define NH   16
#define HD   64
#define QKVN 3072
#define MTOT 8192   // BN*SEQ
// SCALE * log2(e) — folded into Q columns of the QKV GEMM output (fp32).
#define QSCALE_LOG2E 0.18033688011112042f

static __device__ __forceinline__ unsigned short f2bf(float f){
    union { float f; unsigned int i; } v; v.f = f;
    unsigned int r = v.i + 0x7FFFu + ((v.i >> 16) & 1u);   // RNE
    return (unsigned short)(r >> 16);
}

// two fp32 -> one dword of packed bf16 (RNE). gfx950: single v_cvt_pk_bf16_f32.
static __device__ __forceinline__ unsigned int pk2bf(float a, float b){
#if __has_builtin(__builtin_amdgcn_cvt_pk_bf16_f32)
    auto r = __builtin_amdgcn_cvt_pk_bf16_f32(a, b);
    unsigned int u; __builtin_memcpy(&u, &r, 4); return u;
#else
    return (unsigned int)f2bf(a) | ((unsigned int)f2bf(b) << 16);
#endif
}

// raw 2^x (v_exp_f32). Q already carries the SCALE*log2e factor.
static __device__ __forceinline__ float fast_exp2(float x){
#if __has_builtin(__builtin_amdgcn_exp2f)
    return __builtin_amdgcn_exp2f(x);
#else
    return __expf(x * 0.69314718055994531f);
#endif
}

typedef __attribute__((address_space(3))) unsigned int        as3_uint;
typedef const __attribute__((address_space(1))) unsigned int  as1_uint;
static __device__ __forceinline__ void load_lds16(
    const unsigned short* g, unsigned short* l)
{
    __builtin_amdgcn_global_load_lds((as1_uint*)g, (as3_uint*)l, 16, 0, 0);
}

// ---------------- elementwise fp32 -> bf16 (8 elems/thread) ----------------
__global__ __launch_bounds__(256) void convert_f32_bf16(
    const float* __restrict__ in, unsigned short* __restrict__ out)
{
    size_t i = ((size_t)blockIdx.x * 256 + threadIdx.x) * 8;
    f32x4 a = *(const f32x4*)(in + i);
    f32x4 b = *(const f32x4*)(in + i + 4);
    union { unsigned int u[4]; bf16x8 v; } o;
    o.u[0] = pk2bf(a[0], a[1]); o.u[1] = pk2bf(a[2], a[3]);
    o.u[2] = pk2bf(b[0], b[1]); o.u[3] = pk2bf(b[2], b[3]);
    *(bf16x8*)(out + i) = o.v;
}

// ---------------- 32x32 tiled transpose: fp32 in -> bf16 out ---------------
__global__ __launch_bounds__(256) void transpose_f32_to_bf16(
    const float* __restrict__ in, unsigned short* __restrict__ out,
    int in_rs, int out_rs)
{
    __shared__ unsigned short tile[32][33];
    int c0 = blockIdx.x * 32, r0 = blockIdx.y * 32;
    int tx = threadIdx.x, ty = threadIdx.y;
    #pragma unroll
    for (int j = 0; j < 4; j++)
        tile[ty + 8*j][tx] = f2bf(in[(long long)(r0 + ty + 8*j) * in_rs + c0 + tx]);
    __syncthreads();
    #pragma unroll
    for (int j = 0; j < 4; j++)
        out[(long long)(c0 + ty + 8*j) * out_rs + r0 + tx] = tile[tx][ty + 8*j];
}

// ---------------- pack K into fragment order (frags 0..3 of kvpack) --------
__global__ __launch_bounds__(256) void pack_k(
    const unsigned short* __restrict__ qkv, unsigned short* __restrict__ kvpack)
{
    int blk = blockIdx.x;            // bh*64 + t
    int bh = blk >> 6, t = blk & 63;
    int b = bh >> 4, h = bh & 15;
    int tid = threadIdx.x;
    int fr = tid >> 6, l = tid & 63;
    int quad = l >> 4, l15 = l & 15;
    int tb = fr >> 1, d32 = (fr & 1) * 32;
    int row = b*SEQ + t*32 + (l15 >> 2)*8 + (l15 & 3) + 4*tb;
    bf16x8 v = *(const bf16x8*)(qkv + (size_t)row * QKVN + CDIM + h*HD + d32 + quad*8);
    *(bf16x8*)(kvpack + ((size_t)blk*8 + fr)*512 + (size_t)l*8) = v;
}

// ---------------- pack V into fragment order (frags 4..7 of kvpack) --------
__global__ __launch_bounds__(256) void pack_v(
    const unsigned short* __restrict__ qkv, unsigned short* __restrict__ vpack)
{
    __shared__ unsigned short tile[32][66];
    int blk = blockIdx.x;            // bh*64 + t
    int bh = blk >> 6, t = blk & 63;
    int b = bh >> 4, h = bh & 15;
    int tid = threadIdx.x;
    int kk = tid >> 3, dd8 = (tid & 7) * 8;
    bf16x8 v = *(const bf16x8*)(qkv + (size_t)(b*SEQ + t*32 + kk) * QKVN
                                + 2*CDIM + h*HD + dd8);
    #pragma unroll
    for (int e = 0; e < 8; e++) tile[kk][dd8 + e] = v[e];
    __syncthreads();
    int db = tid >> 6, quad = (tid >> 4) & 3, l15 = tid & 15;
    bf16x8 o;
    #pragma unroll
    for (int e = 0; e < 8; e++) o[e] = tile[quad*8 + e][db*16 + l15];
    *(bf16x8*)(vpack + ((size_t)blk*8 + 4 + db)*512 + (size_t)(quad*16 + l15)*8) = o;
}

// ---------------- m97-style LDS-staged GEMM (R8, verified) -----------------
// qcols/qscale: columns [0, qcols) of the output are scaled by qscale in fp32
// BEFORE the bf16 store (used to fold SCALE*log2e into Q at zero precision
// cost). qcols=0 disables.
template<bool OUTF32>
__global__ __launch_bounds__(256) void gemm_lds(
    const unsigned short* __restrict__ A,    // [M,K] bf16
    const unsigned short* __restrict__ BT,   // [N,K] bf16
    void* __restrict__ Cv,                   // [M,Cstride]
    const float* __restrict__ bias,          // [N] or nullptr
    int K, int Cstride, int qcols, float qscale)
{
    __shared__ unsigned short a_lds[128*32];
    __shared__ unsigned short b_lds[128*32];

    int tid  = threadIdx.x;
    int wave = tid >> 6, lane = tid & 63, quad = lane >> 4, l15 = lane & 15;
    int m_blk = blockIdx.y * 128, n_blk = blockIdx.x * 128;

    const unsigned short* ag = A  + (size_t)(m_blk + (tid >> 2)) * K + (tid & 3)*8;
    const unsigned short* bg = BT + (size_t)(n_blk + (tid >> 2)) * K + (tid & 3)*8;
    const size_t row64 = (size_t)64 * K;

    unsigned short* afr = a_lds + ((wave & 1)*64 + l15)*32 + quad*8;
    unsigned short* bfr = b_lds + ((wave >> 1)*64 + l15)*32 + quad*8;

    f32x4 acc[4][4];
    #pragma unroll
    for (int i = 0; i < 4; i++)
        #pragma unroll
        for (int j = 0; j < 4; j++)
            acc[i][j] = f32x4{0.f, 0.f, 0.f, 0.f};

    for (int k0 = 0; k0 < K; k0 += 32) {
        __syncthreads();
        load_lds16(ag,         a_lds + (size_t)tid*8);
        load_lds16(ag + row64, a_lds + 2048 + (size_t)tid*8);
        load_lds16(bg,         b_lds + (size_t)tid*8);
        load_lds16(bg + row64, b_lds + 2048 + (size_t)tid*8);
        ag += 32; bg += 32;
        __syncthreads();

        bf16x8 af[4], bf[4];
        #pragma unroll
        for (int i = 0; i < 4; i++) af[i] = *(const bf16x8*)(afr + 16*i*32);
        #pragma unroll
        for (int i = 0; i < 4; i++) bf[i] = *(const bf16x8*)(bfr + 16*i*32);

        #pragma unroll
        for (int mi = 0; mi < 4; mi++)
            #pragma unroll
            for (int ni = 0; ni < 4; ni++)
                acc[mi][ni] = __builtin_amdgcn_mfma_f32_16x16x32_bf16(
                                  af[mi], bf[ni], acc[mi][ni], 0, 0, 0);
    }

    int m0 = m_blk + (wave & 1) * 64;
    int n0 = n_blk + (wave >> 1) * 64;
    #pragma unroll
    for (int ni = 0; ni < 4; ni++) {
        int col = n0 + 16*ni + l15;
        float bv = bias ? bias[col] : 0.f;
        #pragma unroll
        for (int mi = 0; mi < 4; mi++)
            #pragma unroll
            for (int r = 0; r < 4; r++) {
                int row = m0 + 16*mi + quad*4 + r;
                float v = acc[mi][ni][r] + bv;
                if (col < qcols) v *= qscale;
                if (OUTF32) ((float*)Cv)[(size_t)row * Cstride + col] = v;
                else ((unsigned short*)Cv)[(size_t)row * Cstride + col] = f2bf(v);
            }
    }
}

// ---------------- Flash attention, unnormalized-softmax --------------------
// 4 waves/block, 32 Q rows each (2 strips A/B). KV staged per 32-key tile
// (8KiB) into a 4-buffer LDS ring via global_load_lds, prefetch distance 3,
// counted vmcnt (never 0 in steady state) + raw s_barrier. 18 MFMA per tile
// per wave (8 QK + 8 PV + 2 rowsum). Q carries SCALE*log2e; p = 2^s.

__global__ __launch_bounds__(256, 4) void attn_kernel(
    const unsigned short* __restrict__ qkv,    // [MTOT, 3072] (Q cols used)
    const unsigned short* __restrict__ kvpack, // [64 bh][64 t][8 fr][512]
    unsigned short* __restrict__ ctx)          // [MTOT, 1024]
{
    __shared__ unsigned short kvtile[4][4096];  // 4 x 8 KiB ring

    int tid  = threadIdx.x;
    int wave = tid >> 6, lane = tid & 63, quad = lane >> 4, l15 = lane & 15;
    // chunked XCD swizzle: 1024 blocks, HW round-robins blockIdx%8 across
    // XCDs -> logical block (p&7)*128 + (p>>3) puts each bh's 16 blocks on
    // ONE XCD (bijective since 1024 % 8 == 0). 8 bh/XCD = 4 MiB KV = L2.
    int p  = blockIdx.x;
    int L  = (p & 7) * 128 + (p >> 3);
    int bh = L >> 4;                 // 16 blocks per (b,h)
    int rb = L & 15;
    int b = bh >> 4, h = bh & 15;
    int i0 = rb * 128 + wave * 32;   // this wave's 32 rows (2 strips)

    const unsigned short* qbA =
        qkv + (size_t)(b*SEQ + i0 + l15) * QKVN + h*HD + quad*8;
    const unsigned short* qbB = qbA + (size_t)16 * QKVN;
    bf16x8 qA0 = *(const bf16x8*)(qbA);
    bf16x8 qA1 = *(const bf16x8*)(qbA + 32);
    bf16x8 qB0 = *(const bf16x8*)(qbB);
    bf16x8 qB1 = *(const bf16x8*)(qbB + 32);

    // flat KV stream for this bh: 64 tiles x 4096 shorts, lane-linear.
    const unsigned short* kvg = kvpack + (size_t)bh * 64 * 4096;

#define STAGE(BUF, T) do {                                                     \
        load_lds16(kvg + (size_t)(T)*4096 + tid*8,        &kvtile[BUF][tid*8]);\
        load_lds16(kvg + (size_t)(T)*4096 + 2048 + tid*8,                      \
                   &kvtile[BUF][2048 + tid*8]);                                \
    } while (0)

    // counted-vmcnt sync: own loads retired to <=N, then publish via barrier.
#define SYNC(N) do {                                                           \
        __builtin_amdgcn_sched_barrier(0);                                     \
        asm volatile("s_waitcnt vmcnt(" #N ")" ::: "memory");                  \
        __builtin_amdgcn_s_barrier();                                          \
        __builtin_amdgcn_sched_barrier(0);                                     \
    } while (0)

    const f32x4 zf = {0.f, 0.f, 0.f, 0.f};
    f32x4 oA0 = zf, oA1 = zf, oA2 = zf, oA3 = zf;
    f32x4 oB0 = zf, oB1 = zf, oB2 = zf, oB3 = zf;
    f32x4 lA = zf, lB = zf;

    bf16x8 ones;          // bf16 1.0 everywhere — B-operand for rowsum MFMA
    #pragma unroll
    for (int e = 0; e < 8; e++) ones[e] = (short)0x3F80;

#define ATTN_TILE(LK)                                                              \
    {                                                                              \
        bf16x8 k0a = *(const bf16x8*)((LK));                                       \
        bf16x8 k0b = *(const bf16x8*)((LK) + 512);                                 \
        bf16x8 k1a = *(const bf16x8*)((LK) + 1024);                                \
        bf16x8 k1b = *(const bf16x8*)((LK) + 1536);                                \
        bf16x8 v0  = *(const bf16x8*)((LK) + 2048);                                \
        bf16x8 v1  = *(const bf16x8*)((LK) + 2560);                                \
        bf16x8 v2  = *(const bf16x8*)((LK) + 3072);                                \
        bf16x8 v3  = *(const bf16x8*)((LK) + 3584);                                \
        f32x4 sA0 = __builtin_amdgcn_mfma_f32_16x16x32_bf16(k0a, qA0, zf, 0,0,0);  \
        sA0 = __builtin_amdgcn_mfma_f32_16x16x32_bf16(k0b, qA1, sA0, 0,0,0);       \
        f32x4 sA1 = __builtin_amdgcn_mfma_f32_16x16x32_bf16(k1a, qA0, zf, 0,0,0);  \
        sA1 = __builtin_amdgcn_mfma_f32_16x16x32_bf16(k1b, qA1, sA1, 0,0,0);       \
        f32x4 sB0 = __builtin_amdgcn_mfma_f32_16x16x32_bf16(k0a, qB0, zf, 0,0,0);  \
        sB0 = __builtin_amdgcn_mfma_f32_16x16x32_bf16(k0b, qB1, sB0, 0,0,0);       \
        f32x4 sB1 = __builtin_amdgcn_mfma_f32_16x16x32_bf16(k1a, qB0, zf, 0,0,0);  \
        sB1 = __builtin_amdgcn_mfma_f32_16x16x32_bf16(k1b, qB1, sB1, 0,0,0);       \
        union { unsigned int u[4]; bf16x8 v; } pkA, pkB;                           \
        pkA.u[0] = pk2bf(fast_exp2(sA0[0]), fast_exp2(sA0[1]));                    \
        pkA.u[1] = pk2bf(fast_exp2(sA0[2]), fast_exp2(sA0[3]));                    \
        pkA.u[2] = pk2bf(fast_exp2(sA1[0]), fast_exp2(sA1[1]));                    \
        pkA.u[3] = pk2bf(fast_exp2(sA1[2]), fast_exp2(sA1[3]));                    \
        pkB.u[0] = pk2bf(fast_exp2(sB0[0]), fast_exp2(sB0[1]));                    \
        pkB.u[1] = pk2bf(fast_exp2(sB0[2]), fast_exp2(sB0[3]));                    \
        pkB.u[2] = pk2bf(fast_exp2(sB1[0]), fast_exp2(sB1[1]));                    \
        pkB.u[3] = pk2bf(fast_exp2(sB1[2]), fast_exp2(sB1[3]));                    \
        lA  = __builtin_amdgcn_mfma_f32_16x16x32_bf16(pkA.v, ones, lA, 0,0,0);     \
        lB  = __builtin_amdgcn_mfma_f32_16x16x32_bf16(pkB.v, ones, lB, 0,0,0);     \
        oA0 = __builtin_amdgcn_mfma_f32_16x16x32_bf16(pkA.v, v0, oA0, 0,0,0);      \
        oA1 = __builtin_amdgcn_mfma_f32_16x16x32_bf16(pkA.v, v1, oA1, 0,0,0);      \
        oA2 = __builtin_amdgcn_mfma_f32_16x16x32_bf16(pkA.v, v2, oA2, 0,0,0);      \
        oA3 = __builtin_amdgcn_mfma_f32_16x16x32_bf16(pkA.v, v3, oA3, 0,0,0);      \
        oB0 = __builtin_amdgcn_mfma_f32_16x16x32_bf16(pkB.v, v0, oB0, 0,0,0);      \
        oB1 = __builtin_amdgcn_mfma_f32_16x16x32_bf16(pkB.v, v1, oB1, 0,0,0);      \
        oB2 = __builtin_amdgcn_mfma_f32_16x16x32_bf16(pkB.v, v2, oB2, 0,0,0);      \
        oB3 = __builtin_amdgcn_mfma_f32_16x16x32_bf16(pkB.v, v3, oB3, 0,0,0);      \
    }

    // drain Q loads so loop vmcnt counting sees only STAGE ops
    asm volatile("s_waitcnt vmcnt(0)" ::: "memory");

    STAGE(0, 0); STAGE(1, 1); STAGE(2, 2);      // 6 loads in flight

    const unsigned short* lds0 = &kvtile[0][lane*8];

    // main loop: tiles 0..60; STAGE(t+3) issued each iter (last = tile 63)
    for (int t = 0; t < 61; ++t) {
        SYNC(4);                                 // tile t landed; 4 still flying
        STAGE((t + 3) & 3, t + 3);
        ATTN_TILE(lds0 + (t & 3) * 4096);
    }
    // tail: tiles 61 (vmcnt 4: 62,63 flying), 62 (vmcnt 2), 63 (vmcnt 0)
    SYNC(4); ATTN_TILE(lds0 + 1 * 4096);
    SYNC(2); ATTN_TILE(lds0 + 2 * 4096);
    SYNC(0); ATTN_TILE(lds0 + 3 * 4096);

    // epilogue: l*[r] = full row sum for row quad*4+r (same in every lane)
    #pragma unroll
    for (int r = 0; r < 4; r++) {
        float invA = 1.f / lA[r];
        float invB = 1.f / lB[r];
        int rowA = b*SEQ + i0 + quad*4 + r;
        size_t baseA = (size_t)rowA * CDIM + h*HD + l15;
        size_t baseB = baseA + (size_t)16 * CDIM;
        ctx[baseA]      = f2bf(oA0[r] * invA);
        ctx[baseA + 16] = f2bf(oA1[r] * invA);
        ctx[baseA + 32] = f2bf(oA2[r] * invA);
        ctx[baseA + 48] = f2bf(oA3[r] * invA);
        ctx[baseB]      = f2bf(oB0[r] * invB);
        ctx[baseB + 16] = f2bf(oB1[r] * invB);
        ctx[baseB + 32] = f2bf(oB2[r] * invB);
        ctx[baseB + 48] = f2bf(oB3[r] * invB);
    }
#undef STAGE
#undef SYNC
#undef ATTN_TILE
}

// ---------------------------------------------------------------------------
extern "C" void kernel_launch(void* const* d_in, const int* in_sizes, int n_in,
                              void* d_out, int out_size, void* d_ws, size_t ws_size,
                              hipStream_t stream)
{
    const float* x      = (const float*)d_in[0]; // [8192,1024] fp32
    const float* w_qkv  = (const float*)d_in[1]; // [1024,3072] fp32
    const float* w_proj = (const float*)d_in[2]; // [1024,1024] fp32
    const float* b_proj = (const float*)d_in[3]; // [1024]      fp32
    float* out = (float*)d_out;                  // [8192,1024] fp32

    char* ws = (char*)d_ws;                                      // 104 MiB used
    unsigned short* qkv    = (unsigned short*)(ws);              // [0,48M)
    unsigned short* ctx    = (unsigned short*)(ws + 50331648);   // [48M,64M)
    unsigned short* kvpack = (unsigned short*)(ws + 67108864);   // [64M,96M)
    unsigned short* xb     = (unsigned short*)(ws + 83886080);   // alias: xb dead
                                                                 // before pack_* write
    unsigned short* wqkvT  = (unsigned short*)(ws + 100663296);  // [96M,102M)
    unsigned short* wprojT = (unsigned short*)(ws + 106954752);  // [102M,104M)

    dim3 tb(32, 8);
    transpose_f32_to_bf16<<<dim3(QKVN/32, CDIM/32), tb, 0, stream>>>(
        w_qkv, wqkvT, QKVN, CDIM);
    transpose_f32_to_bf16<<<dim3(CDIM/32, CDIM/32), tb, 0, stream>>>(
        w_proj, wprojT, CDIM, CDIM);

    // xb = bf16(x)
    convert_f32_bf16<<<dim3(MTOT*CDIM/2048), 256, 0, stream>>>(x, xb);

    // qkv = xb @ wqkvT   [8192, 3072] bf16; Q cols pre-scaled by SCALE*log2e
    gemm_lds<false><<<dim3(QKVN/128, MTOT/128), 256, 0, stream>>>(
        xb, wqkvT, qkv, nullptr, CDIM, QKVN, CDIM, QSCALE_LOG2E);

    // pack K and V into fragment-consumption order (overwrites xb region)
    pack_k<<<dim3(64*64), 256, 0, stream>>>(qkv, kvpack);
    pack_v<<<dim3(64*64), 256, 0, stream>>>(qkv, kvpack);

    // flash attention -> ctx [8192, 1024] bf16
    attn_kernel<<<dim3(BN * NH * (SEQ/128)), 256, 0, stream>>>(
        qkv, kvpack, ctx);

    // out = ctx @ wprojT + b_proj   (fp32 out)
    gemm_lds<true><<<dim3(CDIM/128, MTOT/128), 256, 0, stream>>>(
        ctx, wprojT, out, b_proj, CDIM, CDIM, 0, 1.0f);
}

// Round 6
// 276.607 us; speedup vs baseline: 1.2803x; 1.0745x over previous
//
#include <hip/hip_runtime.h>
#include <hip/hip_bf16.h>

// Attention_919123001813 — B=4, N=2048, DIM=1024, H=16, HD=64, SCALE=1/8
// Round 16: attn is issue-saturated (~96% MFMA+VALU) at 87.6us — park it.
// Attack the other 210us:
//  (a) fuse pack_k/pack_v into the QKV-GEMM epilogue: K/V output regions are
//      written DIRECTLY in fragment order (K: lane-coalesced 16B chunks;
//      V: the 4 acc r-values = 4 consecutive frag elems = one aligned 8B
//      store). Deletes 2 kernels + 64MB of traffic + 32MB of linear stores.
//      Index algebra verified against pack_k/pack_v derivations.
//  (b) bijective chunked XCD swizzle on both GEMMs (nwg%8==0): each XCD gets
//      a contiguous m-chunk -> B-panel stays L2-resident (catalog T1).
//  (c) xb moved to alias ctx (its old slot is now live kvpack; ctx is only
//      written by attn AFTER gemm1 consumed xb).
// attn kernel unchanged from R15 (verified counted-vmcnt 4-ring).

typedef short bf16x8 __attribute__((ext_vector_type(8)));
typedef float f32x4  __attribute__((ext_vector_type(4)));

#define BN   4
#define SEQ  2048
#define CDIM 1024
#define NH   16
#define HD   64
#define QKVN 3072
#define MTOT 8192   // BN*SEQ
// SCALE * log2(e) — folded into Q columns of the QKV GEMM output (fp32).
#define QSCALE_LOG2E 0.18033688011112042f

static __device__ __forceinline__ unsigned short f2bf(float f){
    union { float f; unsigned int i; } v; v.f = f;
    unsigned int r = v.i + 0x7FFFu + ((v.i >> 16) & 1u);   // RNE
    return (unsigned short)(r >> 16);
}

// two fp32 -> one dword of packed bf16 (RNE). gfx950: single v_cvt_pk_bf16_f32.
static __device__ __forceinline__ unsigned int pk2bf(float a, float b){
#if __has_builtin(__builtin_amdgcn_cvt_pk_bf16_f32)
    auto r = __builtin_amdgcn_cvt_pk_bf16_f32(a, b);
    unsigned int u; __builtin_memcpy(&u, &r, 4); return u;
#else
    return (unsigned int)f2bf(a) | ((unsigned int)f2bf(b) << 16);
#endif
}

// raw 2^x (v_exp_f32). Q already carries the SCALE*log2e factor.
static __device__ __forceinline__ float fast_exp2(float x){
#if __has_builtin(__builtin_amdgcn_exp2f)
    return __builtin_amdgcn_exp2f(x);
#else
    return __expf(x * 0.69314718055994531f);
#endif
}

typedef __attribute__((address_space(3))) unsigned int        as3_uint;
typedef const __attribute__((address_space(1))) unsigned int  as1_uint;
static __device__ __forceinline__ void load_lds16(
    const unsigned short* g, unsigned short* l)
{
    __builtin_amdgcn_global_load_lds((as1_uint*)g, (as3_uint*)l, 16, 0, 0);
}

// ---------------- elementwise fp32 -> bf16 (8 elems/thread) ----------------
__global__ __launch_bounds__(256) void convert_f32_bf16(
    const float* __restrict__ in, unsigned short* __restrict__ out)
{
    size_t i = ((size_t)blockIdx.x * 256 + threadIdx.x) * 8;
    f32x4 a = *(const f32x4*)(in + i);
    f32x4 b = *(const f32x4*)(in + i + 4);
    union { unsigned int u[4]; bf16x8 v; } o;
    o.u[0] = pk2bf(a[0], a[1]); o.u[1] = pk2bf(a[2], a[3]);
    o.u[2] = pk2bf(b[0], b[1]); o.u[3] = pk2bf(b[2], b[3]);
    *(bf16x8*)(out + i) = o.v;
}

// ---------------- 32x32 tiled transpose: fp32 in -> bf16 out ---------------
__global__ __launch_bounds__(256) void transpose_f32_to_bf16(
    const float* __restrict__ in, unsigned short* __restrict__ out,
    int in_rs, int out_rs)
{
    __shared__ unsigned short tile[32][33];
    int c0 = blockIdx.x * 32, r0 = blockIdx.y * 32;
    int tx = threadIdx.x, ty = threadIdx.y;
    #pragma unroll
    for (int j = 0; j < 4; j++)
        tile[ty + 8*j][tx] = f2bf(in[(long long)(r0 + ty + 8*j) * in_rs + c0 + tx]);
    __syncthreads();
    #pragma unroll
    for (int j = 0; j < 4; j++)
        out[(long long)(c0 + ty + 8*j) * out_rs + r0 + tx] = tile[tx][ty + 8*j];
}

// ---------------- m97-style LDS-staged GEMM ---------------------------------
// MODE 0: C = A@BT^T + bias, fp32 out (proj GEMM).
// MODE 1: fused QKV: cols [0,1024) -> qkv linear bf16, scaled by
//         SCALE*log2e (fp32, pre-round); cols [1024,2048) -> kvpack K frags;
//         cols [2048,3072) -> kvpack V frags. Replaces pack_k/pack_v.
// NX = grid width in 128-tiles (compile-time for cheap div in swizzle).
template<int MODE, int NX>
__global__ __launch_bounds__(256) void gemm_lds(
    const unsigned short* __restrict__ A,    // [M,K] bf16
    const unsigned short* __restrict__ BT,   // [N,K] bf16
    void* __restrict__ Cv,                   // MODE0: float*; MODE1: ushort* qkv
    unsigned short* __restrict__ kvpack,     // MODE1 only
    const float* __restrict__ bias,          // MODE0 only (or nullptr)
    int K, int Cstride)
{
    __shared__ unsigned short a_lds[128*32];
    __shared__ unsigned short b_lds[128*32];

    int tid  = threadIdx.x;
    int wave = tid >> 6, lane = tid & 63, quad = lane >> 4, l15 = lane & 15;

    // bijective chunked XCD swizzle (nwg % 8 == 0): XCD x gets logical
    // blocks [x*cpx, (x+1)*cpx) -> contiguous m-rows share the B panel in L2.
    int nwg = gridDim.x;
    int cpx = nwg >> 3;
    int bid = blockIdx.x;
    int swz = (bid & 7) * cpx + (bid >> 3);
    int m_blk = (swz / NX) * 128, n_blk = (swz % NX) * 128;

    const unsigned short* ag = A  + (size_t)(m_blk + (tid >> 2)) * K + (tid & 3)*8;
    const unsigned short* bg = BT + (size_t)(n_blk + (tid >> 2)) * K + (tid & 3)*8;
    const size_t row64 = (size_t)64 * K;

    unsigned short* afr = a_lds + ((wave & 1)*64 + l15)*32 + quad*8;
    unsigned short* bfr = b_lds + ((wave >> 1)*64 + l15)*32 + quad*8;

    f32x4 acc[4][4];
    #pragma unroll
    for (int i = 0; i < 4; i++)
        #pragma unroll
        for (int j = 0; j < 4; j++)
            acc[i][j] = f32x4{0.f, 0.f, 0.f, 0.f};

    for (int k0 = 0; k0 < K; k0 += 32) {
        __syncthreads();
        load_lds16(ag,         a_lds + (size_t)tid*8);
        load_lds16(ag + row64, a_lds + 2048 + (size_t)tid*8);
        load_lds16(bg,         b_lds + (size_t)tid*8);
        load_lds16(bg + row64, b_lds + 2048 + (size_t)tid*8);
        ag += 32; bg += 32;
        __syncthreads();

        bf16x8 af[4], bf[4];
        #pragma unroll
        for (int i = 0; i < 4; i++) af[i] = *(const bf16x8*)(afr + 16*i*32);
        #pragma unroll
        for (int i = 0; i < 4; i++) bf[i] = *(const bf16x8*)(bfr + 16*i*32);

        #pragma unroll
        for (int mi = 0; mi < 4; mi++)
            #pragma unroll
            for (int ni = 0; ni < 4; ni++)
                acc[mi][ni] = __builtin_amdgcn_mfma_f32_16x16x32_bf16(
                                  af[mi], bf[ni], acc[mi][ni], 0, 0, 0);
    }

    int m0 = m_blk + (wave & 1) * 64;
    int n0 = n_blk + (wave >> 1) * 64;

    if constexpr (MODE == 0) {
        float* C = (float*)Cv;
        #pragma unroll
        for (int ni = 0; ni < 4; ni++) {
            int col = n0 + 16*ni + l15;
            float bv = bias ? bias[col] : 0.f;
            #pragma unroll
            for (int mi = 0; mi < 4; mi++)
                #pragma unroll
                for (int r = 0; r < 4; r++) {
                    int row = m0 + 16*mi + quad*4 + r;
                    C[(size_t)row * Cstride + col] = acc[mi][ni][r] + bv;
                }
        }
    } else {
        unsigned short* qkvo = (unsigned short*)Cv;
        int rg = n0 >> 10;             // 0=Q, 1=K, 2=V (uniform per wave)
        if (rg == 0) {
            // Q: linear bf16, pre-scaled by SCALE*log2e in fp32
            #pragma unroll
            for (int ni = 0; ni < 4; ni++) {
                int col = n0 + 16*ni + l15;
                #pragma unroll
                for (int mi = 0; mi < 4; mi++)
                    #pragma unroll
                    for (int r = 0; r < 4; r++) {
                        int row = m0 + 16*mi + quad*4 + r;
                        qkvo[(size_t)row * Cstride + col] =
                            f2bf(acc[mi][ni][r] * QSCALE_LOG2E);
                    }
            }
        } else if (rg == 1) {
            // K -> kvpack frags 0..3. Element K[key][d] of tile (bh,t) lives
            // at frag fr = ((key>>2)&1)*2 + (d>>5),
            //    lane = ((d&31)>>3)*16 + (key>>3)*4 + (key&3), elem = d&7.
            #pragma unroll
            for (int ni = 0; ni < 4; ni++) {
                int col = n0 + 16*ni + l15 - 1024;     // 0..1023
                int h = col >> 6, d = col & 63;
                int quadd = (d & 31) >> 3, e = d & 7, dhi = d >> 5;
                #pragma unroll
                for (int mi = 0; mi < 4; mi++)
                    #pragma unroll
                    for (int r = 0; r < 4; r++) {
                        int row = m0 + 16*mi + quad*4 + r;
                        int b = row >> 11, t = (row & 2047) >> 5, key = row & 31;
                        int tb = (key >> 2) & 1;
                        int l15a = ((key >> 3) << 2) + (key & 3);
                        size_t addr =
                            ((size_t)(((b*16 + h)*64 + t)*8 + tb*2 + dhi))*512
                            + (size_t)(quadd*16 + l15a)*8 + e;
                        kvpack[addr] = f2bf(acc[mi][ni][r]);
                    }
            }
        } else {
            // V -> kvpack frags 4..7. Element V[key][d] lives at
            // frag 4 + (d>>4), lane = (key>>3)*16 + (d&15), elem = key&7.
            // The 4 acc r-values are keys key0..key0+3 with key0&7 in {0,4}
            // -> 4 consecutive elems -> one aligned 8B store.
            #pragma unroll
            for (int ni = 0; ni < 4; ni++) {
                int col = n0 + 16*ni + l15 - 2048;     // 0..1023
                int h = col >> 6, d = col & 63;
                int db = d >> 4, l15v = d & 15;
                #pragma unroll
                for (int mi = 0; mi < 4; mi++) {
                    int row0 = m0 + 16*mi + quad*4;    // r = 0
                    int b = row0 >> 11, t = (row0 & 2047) >> 5, key0 = row0 & 31;
                    int quadv = key0 >> 3, e0 = key0 & 7;
                    size_t addr =
                        ((size_t)(((b*16 + h)*64 + t)*8 + 4 + db))*512
                        + (size_t)(quadv*16 + l15v)*8 + e0;
                    union { unsigned int u[2]; unsigned long long ull; } o;
                    o.u[0] = pk2bf(acc[mi][ni][0], acc[mi][ni][1]);
                    o.u[1] = pk2bf(acc[mi][ni][2], acc[mi][ni][3]);
                    *(unsigned long long*)(kvpack + addr) = o.ull;
                }
            }
        }
    }
}

// ---------------- Flash attention, unnormalized-softmax --------------------
// 4 waves/block, 32 Q rows each (2 strips A/B). KV staged per 32-key tile
// (8KiB) into a 4-buffer LDS ring via global_load_lds, prefetch distance 3,
// counted vmcnt (never 0 in steady state) + raw s_barrier. 18 MFMA per tile
// per wave (8 QK + 8 PV + 2 rowsum). Q carries SCALE*log2e; p = 2^s.

__global__ __launch_bounds__(256, 4) void attn_kernel(
    const unsigned short* __restrict__ qkv,    // [MTOT, 3072] (Q cols used)
    const unsigned short* __restrict__ kvpack, // [64 bh][64 t][8 fr][512]
    unsigned short* __restrict__ ctx)          // [MTOT, 1024]
{
    __shared__ unsigned short kvtile[4][4096];  // 4 x 8 KiB ring

    int tid  = threadIdx.x;
    int wave = tid >> 6, lane = tid & 63, quad = lane >> 4, l15 = lane & 15;
    // chunked XCD swizzle: 1024 blocks, HW round-robins blockIdx%8 across
    // XCDs -> logical block (p&7)*128 + (p>>3) puts each bh's 16 blocks on
    // ONE XCD (bijective since 1024 % 8 == 0). 8 bh/XCD = 4 MiB KV = L2.
    int p  = blockIdx.x;
    int L  = (p & 7) * 128 + (p >> 3);
    int bh = L >> 4;                 // 16 blocks per (b,h)
    int rb = L & 15;
    int b = bh >> 4, h = bh & 15;
    int i0 = rb * 128 + wave * 32;   // this wave's 32 rows (2 strips)

    const unsigned short* qbA =
        qkv + (size_t)(b*SEQ + i0 + l15) * QKVN + h*HD + quad*8;
    const unsigned short* qbB = qbA + (size_t)16 * QKVN;
    bf16x8 qA0 = *(const bf16x8*)(qbA);
    bf16x8 qA1 = *(const bf16x8*)(qbA + 32);
    bf16x8 qB0 = *(const bf16x8*)(qbB);
    bf16x8 qB1 = *(const bf16x8*)(qbB + 32);

    // flat KV stream for this bh: 64 tiles x 4096 shorts, lane-linear.
    const unsigned short* kvg = kvpack + (size_t)bh * 64 * 4096;

#define STAGE(BUF, T) do {                                                     \
        load_lds16(kvg + (size_t)(T)*4096 + tid*8,        &kvtile[BUF][tid*8]);\
        load_lds16(kvg + (size_t)(T)*4096 + 2048 + tid*8,                      \
                   &kvtile[BUF][2048 + tid*8]);                                \
    } while (0)

    // counted-vmcnt sync: own loads retired to <=N, then publish via barrier.
#define SYNC(N) do {                                                           \
        __builtin_amdgcn_sched_barrier(0);                                     \
        asm volatile("s_waitcnt vmcnt(" #N ")" ::: "memory");                  \
        __builtin_amdgcn_s_barrier();                                          \
        __builtin_amdgcn_sched_barrier(0);                                     \
    } while (0)

    const f32x4 zf = {0.f, 0.f, 0.f, 0.f};
    f32x4 oA0 = zf, oA1 = zf, oA2 = zf, oA3 = zf;
    f32x4 oB0 = zf, oB1 = zf, oB2 = zf, oB3 = zf;
    f32x4 lA = zf, lB = zf;

    bf16x8 ones;          // bf16 1.0 everywhere — B-operand for rowsum MFMA
    #pragma unroll
    for (int e = 0; e < 8; e++) ones[e] = (short)0x3F80;

#define ATTN_TILE(LK)                                                              \
    {                                                                              \
        bf16x8 k0a = *(const bf16x8*)((LK));                                       \
        bf16x8 k0b = *(const bf16x8*)((LK) + 512);                                 \
        bf16x8 k1a = *(const bf16x8*)((LK) + 1024);                                \
        bf16x8 k1b = *(const bf16x8*)((LK) + 1536);                                \
        bf16x8 v0  = *(const bf16x8*)((LK) + 2048);                                \
        bf16x8 v1  = *(const bf16x8*)((LK) + 2560);                                \
        bf16x8 v2  = *(const bf16x8*)((LK) + 3072);                                \
        bf16x8 v3  = *(const bf16x8*)((LK) + 3584);                                \
        f32x4 sA0 = __builtin_amdgcn_mfma_f32_16x16x32_bf16(k0a, qA0, zf, 0,0,0);  \
        sA0 = __builtin_amdgcn_mfma_f32_16x16x32_bf16(k0b, qA1, sA0, 0,0,0);       \
        f32x4 sA1 = __builtin_amdgcn_mfma_f32_16x16x32_bf16(k1a, qA0, zf, 0,0,0);  \
        sA1 = __builtin_amdgcn_mfma_f32_16x16x32_bf16(k1b, qA1, sA1, 0,0,0);       \
        f32x4 sB0 = __builtin_amdgcn_mfma_f32_16x16x32_bf16(k0a, qB0, zf, 0,0,0);  \
        sB0 = __builtin_amdgcn_mfma_f32_16x16x32_bf16(k0b, qB1, sB0, 0,0,0);       \
        f32x4 sB1 = __builtin_amdgcn_mfma_f32_16x16x32_bf16(k1a, qB0, zf, 0,0,0);  \
        sB1 = __builtin_amdgcn_mfma_f32_16x16x32_bf16(k1b, qB1, sB1, 0,0,0);       \
        union { unsigned int u[4]; bf16x8 v; } pkA, pkB;                           \
        pkA.u[0] = pk2bf(fast_exp2(sA0[0]), fast_exp2(sA0[1]));                    \
        pkA.u[1] = pk2bf(fast_exp2(sA0[2]), fast_exp2(sA0[3]));                    \
        pkA.u[2] = pk2bf(fast_exp2(sA1[0]), fast_exp2(sA1[1]));                    \
        pkA.u[3] = pk2bf(fast_exp2(sA1[2]), fast_exp2(sA1[3]));                    \
        pkB.u[0] = pk2bf(fast_exp2(sB0[0]), fast_exp2(sB0[1]));                    \
        pkB.u[1] = pk2bf(fast_exp2(sB0[2]), fast_exp2(sB0[3]));                    \
        pkB.u[2] = pk2bf(fast_exp2(sB1[0]), fast_exp2(sB1[1]));                    \
        pkB.u[3] = pk2bf(fast_exp2(sB1[2]), fast_exp2(sB1[3]));                    \
        lA  = __builtin_amdgcn_mfma_f32_16x16x32_bf16(pkA.v, ones, lA, 0,0,0);     \
        lB  = __builtin_amdgcn_mfma_f32_16x16x32_bf16(pkB.v, ones, lB, 0,0,0);     \
        oA0 = __builtin_amdgcn_mfma_f32_16x16x32_bf16(pkA.v, v0, oA0, 0,0,0);      \
        oA1 = __builtin_amdgcn_mfma_f32_16x16x32_bf16(pkA.v, v1, oA1, 0,0,0);      \
        oA2 = __builtin_amdgcn_mfma_f32_16x16x32_bf16(pkA.v, v2, oA2, 0,0,0);      \
        oA3 = __builtin_amdgcn_mfma_f32_16x16x32_bf16(pkA.v, v3, oA3, 0,0,0);      \
        oB0 = __builtin_amdgcn_mfma_f32_16x16x32_bf16(pkB.v, v0, oB0, 0,0,0);      \
        oB1 = __builtin_amdgcn_mfma_f32_16x16x32_bf16(pkB.v, v1, oB1, 0,0,0);      \
        oB2 = __builtin_amdgcn_mfma_f32_16x16x32_bf16(pkB.v, v2, oB2, 0,0,0);      \
        oB3 = __builtin_amdgcn_mfma_f32_16x16x32_bf16(pkB.v, v3, oB3, 0,0,0);      \
    }

    // drain Q loads so loop vmcnt counting sees only STAGE ops
    asm volatile("s_waitcnt vmcnt(0)" ::: "memory");

    STAGE(0, 0); STAGE(1, 1); STAGE(2, 2);      // 6 loads in flight

    const unsigned short* lds0 = &kvtile[0][lane*8];

    // main loop: tiles 0..60; STAGE(t+3) issued each iter (last = tile 63)
    for (int t = 0; t < 61; ++t) {
        SYNC(4);                                 // tile t landed; 4 still flying
        STAGE((t + 3) & 3, t + 3);
        ATTN_TILE(lds0 + (t & 3) * 4096);
    }
    // tail: tiles 61 (vmcnt 4: 62,63 flying), 62 (vmcnt 2), 63 (vmcnt 0)
    SYNC(4); ATTN_TILE(lds0 + 1 * 4096);
    SYNC(2); ATTN_TILE(lds0 + 2 * 4096);
    SYNC(0); ATTN_TILE(lds0 + 3 * 4096);

    // epilogue: l*[r] = full row sum for row quad*4+r (same in every lane)
    #pragma unroll
    for (int r = 0; r < 4; r++) {
        float invA = 1.f / lA[r];
        float invB = 1.f / lB[r];
        int rowA = b*SEQ + i0 + quad*4 + r;
        size_t baseA = (size_t)rowA * CDIM + h*HD + l15;
        size_t baseB = baseA + (size_t)16 * CDIM;
        ctx[baseA]      = f2bf(oA0[r] * invA);
        ctx[baseA + 16] = f2bf(oA1[r] * invA);
        ctx[baseA + 32] = f2bf(oA2[r] * invA);
        ctx[baseA + 48] = f2bf(oA3[r] * invA);
        ctx[baseB]      = f2bf(oB0[r] * invB);
        ctx[baseB + 16] = f2bf(oB1[r] * invB);
        ctx[baseB + 32] = f2bf(oB2[r] * invB);
        ctx[baseB + 48] = f2bf(oB3[r] * invB);
    }
#undef STAGE
#undef SYNC
#undef ATTN_TILE
}

// ---------------------------------------------------------------------------
extern "C" void kernel_launch(void* const* d_in, const int* in_sizes, int n_in,
                              void* d_out, int out_size, void* d_ws, size_t ws_size,
                              hipStream_t stream)
{
    const float* x      = (const float*)d_in[0]; // [8192,1024] fp32
    const float* w_qkv  = (const float*)d_in[1]; // [1024,3072] fp32
    const float* w_proj = (const float*)d_in[2]; // [1024,1024] fp32
    const float* b_proj = (const float*)d_in[3]; // [1024]      fp32
    float* out = (float*)d_out;                  // [8192,1024] fp32

    char* ws = (char*)d_ws;                                      // 104 MiB used
    unsigned short* qkv    = (unsigned short*)(ws);              // [0,48M)
    unsigned short* ctx    = (unsigned short*)(ws + 50331648);   // [48M,64M)
    unsigned short* xb     = ctx;    // alias: xb consumed by gemm1 before attn
                                     // writes ctx
    unsigned short* kvpack = (unsigned short*)(ws + 67108864);   // [64M,96M)
    unsigned short* wqkvT  = (unsigned short*)(ws + 100663296);  // [96M,102M)
    unsigned short* wprojT = (unsigned short*)(ws + 106954752);  // [102M,104M)

    dim3 tb(32, 8);
    transpose_f32_to_bf16<<<dim3(QKVN/32, CDIM/32), tb, 0, stream>>>(
        w_qkv, wqkvT, QKVN, CDIM);
    transpose_f32_to_bf16<<<dim3(CDIM/32, CDIM/32), tb, 0, stream>>>(
        w_proj, wprojT, CDIM, CDIM);

    // xb = bf16(x)
    convert_f32_bf16<<<dim3(MTOT*CDIM/2048), 256, 0, stream>>>(x, xb);

    // fused QKV GEMM: Q -> qkv linear (scaled), K/V -> kvpack fragment order
    // grid = (3072/128) x (8192/128) = 24 x 64 = 1536 blocks (1536 % 8 == 0)
    gemm_lds<1, QKVN/128><<<dim3((QKVN/128)*(MTOT/128)), 256, 0, stream>>>(
        xb, wqkvT, qkv, kvpack, nullptr, CDIM, QKVN);

    // flash attention -> ctx [8192, 1024] bf16 (overwrites xb region)
    attn_kernel<<<dim3(BN * NH * (SEQ/128)), 256, 0, stream>>>(
        qkv, kvpack, ctx);

    // out = ctx @ wprojT + b_proj   (fp32 out)
    // grid = (1024/128) x (8192/128) = 8 x 64 = 512 blocks (512 % 8 == 0)
    gemm_lds<0, CDIM/128><<<dim3((CDIM/128)*(MTOT/128)), 256, 0, stream>>>(
        ctx, wprojT, out, nullptr, b_proj, CDIM, CDIM);
}

// Round 7
// 275.771 us; speedup vs baseline: 1.2841x; 1.0030x over previous
//
#include <hip/hip_runtime.h>
#include <hip/hip_bf16.h>

// Attention_919123001813 — B=4, N=2048, DIM=1024, H=16, HD=64, SCALE=1/8
// Round 17: GEMMs still use the __syncthreads-sandwich staging loop whose
// vmcnt(0) barrier drain is the m97 structure's known ~20% stall. Port the
// R15-verified counted-vmcnt ring to gemm_lds:
//  - 3-buffer LDS ring (48KB, keeps ~3 blocks/CU; NOT 4xBK=64 -> m132 cliff)
//  - prefetch distance 2, SYNC(4) steady / SYNC(4),SYNC(0) tail
//  - ledger: 4 loads/thread/K-step; iter t waits own outstanding <=4 (tile t
//    retired in-order; barrier publishes all waves), stages t+2 into buffer
//    (t-1)%3 whose reads completed before this barrier (lgkmcnt before MFMA
//    in iter t-1 + barrier ordering). Same safety argument as R15 attn.
// Epilogues (incl. fused K/V pack), attn kernel, layouts: identical to R16.

typedef short bf16x8 __attribute__((ext_vector_type(8)));
typedef float f32x4  __attribute__((ext_vector_type(4)));

#define BN   4
#define SEQ  2048
#define CDIM 1024
#define NH   16
#define HD   64
#define QKVN 3072
#define MTOT 8192   // BN*SEQ
// SCALE * log2(e) — folded into Q columns of the QKV GEMM output (fp32).
#define QSCALE_LOG2E 0.18033688011112042f

static __device__ __forceinline__ unsigned short f2bf(float f){
    union { float f; unsigned int i; } v; v.f = f;
    unsigned int r = v.i + 0x7FFFu + ((v.i >> 16) & 1u);   // RNE
    return (unsigned short)(r >> 16);
}

// two fp32 -> one dword of packed bf16 (RNE). gfx950: single v_cvt_pk_bf16_f32.
static __device__ __forceinline__ unsigned int pk2bf(float a, float b){
#if __has_builtin(__builtin_amdgcn_cvt_pk_bf16_f32)
    auto r = __builtin_amdgcn_cvt_pk_bf16_f32(a, b);
    unsigned int u; __builtin_memcpy(&u, &r, 4); return u;
#else
    return (unsigned int)f2bf(a) | ((unsigned int)f2bf(b) << 16);
#endif
}

// raw 2^x (v_exp_f32). Q already carries the SCALE*log2e factor.
static __device__ __forceinline__ float fast_exp2(float x){
#if __has_builtin(__builtin_amdgcn_exp2f)
    return __builtin_amdgcn_exp2f(x);
#else
    return __expf(x * 0.69314718055994531f);
#endif
}

typedef __attribute__((address_space(3))) unsigned int        as3_uint;
typedef const __attribute__((address_space(1))) unsigned int  as1_uint;
static __device__ __forceinline__ void load_lds16(
    const unsigned short* g, unsigned short* l)
{
    __builtin_amdgcn_global_load_lds((as1_uint*)g, (as3_uint*)l, 16, 0, 0);
}

// counted-vmcnt sync: own loads retired to <=N, then publish via barrier.
#define SYNC(N) do {                                                           \
        __builtin_amdgcn_sched_barrier(0);                                     \
        asm volatile("s_waitcnt vmcnt(" #N ")" ::: "memory");                  \
        __builtin_amdgcn_s_barrier();                                          \
        __builtin_amdgcn_sched_barrier(0);                                     \
    } while (0)

// ---------------- elementwise fp32 -> bf16 (8 elems/thread) ----------------
__global__ __launch_bounds__(256) void convert_f32_bf16(
    const float* __restrict__ in, unsigned short* __restrict__ out)
{
    size_t i = ((size_t)blockIdx.x * 256 + threadIdx.x) * 8;
    f32x4 a = *(const f32x4*)(in + i);
    f32x4 b = *(const f32x4*)(in + i + 4);
    union { unsigned int u[4]; bf16x8 v; } o;
    o.u[0] = pk2bf(a[0], a[1]); o.u[1] = pk2bf(a[2], a[3]);
    o.u[2] = pk2bf(b[0], b[1]); o.u[3] = pk2bf(b[2], b[3]);
    *(bf16x8*)(out + i) = o.v;
}

// ---------------- 32x32 tiled transpose: fp32 in -> bf16 out ---------------
__global__ __launch_bounds__(256) void transpose_f32_to_bf16(
    const float* __restrict__ in, unsigned short* __restrict__ out,
    int in_rs, int out_rs)
{
    __shared__ unsigned short tile[32][33];
    int c0 = blockIdx.x * 32, r0 = blockIdx.y * 32;
    int tx = threadIdx.x, ty = threadIdx.y;
    #pragma unroll
    for (int j = 0; j < 4; j++)
        tile[ty + 8*j][tx] = f2bf(in[(long long)(r0 + ty + 8*j) * in_rs + c0 + tx]);
    __syncthreads();
    #pragma unroll
    for (int j = 0; j < 4; j++)
        out[(long long)(c0 + ty + 8*j) * out_rs + r0 + tx] = tile[tx][ty + 8*j];
}

// ---------------- m97-style GEMM with counted-vmcnt 3-ring ------------------
// MODE 0: C = A@BT^T + bias, fp32 out (proj GEMM).
// MODE 1: fused QKV: cols [0,1024) -> qkv linear bf16, scaled by
//         SCALE*log2e (fp32, pre-round); cols [1024,2048) -> kvpack K frags;
//         cols [2048,3072) -> kvpack V frags.
// NX = grid width in 128-tiles (compile-time for cheap div in swizzle).
template<int MODE, int NX>
__global__ __launch_bounds__(256) void gemm_lds(
    const unsigned short* __restrict__ A,    // [M,K] bf16
    const unsigned short* __restrict__ BT,   // [N,K] bf16
    void* __restrict__ Cv,                   // MODE0: float*; MODE1: ushort* qkv
    unsigned short* __restrict__ kvpack,     // MODE1 only
    const float* __restrict__ bias,          // MODE0 only (or nullptr)
    int K, int Cstride)
{
    __shared__ unsigned short a_lds[3][4096];   // 3 x 8 KiB ring (A)
    __shared__ unsigned short b_lds[3][4096];   // 3 x 8 KiB ring (B)

    int tid  = threadIdx.x;
    int wave = tid >> 6, lane = tid & 63, quad = lane >> 4, l15 = lane & 15;

    // bijective chunked XCD swizzle (nwg % 8 == 0): XCD x gets logical
    // blocks [x*cpx, (x+1)*cpx) -> contiguous m-rows share the B panel in L2.
    int nwg = gridDim.x;
    int cpx = nwg >> 3;
    int bid = blockIdx.x;
    int swz = (bid & 7) * cpx + (bid >> 3);
    int m_blk = (swz / NX) * 128, n_blk = (swz % NX) * 128;

    const unsigned short* ag = A  + (size_t)(m_blk + (tid >> 2)) * K + (tid & 3)*8;
    const unsigned short* bg = BT + (size_t)(n_blk + (tid >> 2)) * K + (tid & 3)*8;
    const size_t row64 = (size_t)64 * K;

#define GSTAGE(BUF, T) do {                                                    \
        const unsigned short* ag_ = ag + (size_t)(T)*32;                       \
        const unsigned short* bg_ = bg + (size_t)(T)*32;                       \
        load_lds16(ag_,         &a_lds[BUF][tid*8]);                           \
        load_lds16(ag_ + row64, &a_lds[BUF][2048 + tid*8]);                    \
        load_lds16(bg_,         &b_lds[BUF][tid*8]);                           \
        load_lds16(bg_ + row64, &b_lds[BUF][2048 + tid*8]);                    \
    } while (0)

    const unsigned short* afr = &a_lds[0][((wave & 1)*64 + l15)*32 + quad*8];
    const unsigned short* bfr = &b_lds[0][((wave >> 1)*64 + l15)*32 + quad*8];

    f32x4 acc[4][4];
    #pragma unroll
    for (int i = 0; i < 4; i++)
        #pragma unroll
        for (int j = 0; j < 4; j++)
            acc[i][j] = f32x4{0.f, 0.f, 0.f, 0.f};

    int nk = K >> 5;                      // K-steps of 32
    GSTAGE(0, 0);
    GSTAGE(1, 1);                         // 8 loads in flight (tiles 0,1)

    int buf = 0, nbuf = 2;                // buf = t%3; nbuf = (t+2)%3
    for (int t = 0; t < nk; ++t) {
        if (t + 2 < nk) {
            SYNC(4);                      // tile t landed; tile t+1 flying
            GSTAGE(nbuf, t + 2);          // into buffer (t-1)%3 (reads done)
        } else if (t + 1 < nk) {
            SYNC(4);                      // tile t landed; t+1 flying
        } else {
            SYNC(0);                      // last tile landed
        }

        int bo = buf * 4096;
        bf16x8 af[4], bfv[4];
        #pragma unroll
        for (int i = 0; i < 4; i++) af[i]  = *(const bf16x8*)(afr + bo + 16*i*32);
        #pragma unroll
        for (int i = 0; i < 4; i++) bfv[i] = *(const bf16x8*)(bfr + bo + 16*i*32);

        #pragma unroll
        for (int mi = 0; mi < 4; mi++)
            #pragma unroll
            for (int ni = 0; ni < 4; ni++)
                acc[mi][ni] = __builtin_amdgcn_mfma_f32_16x16x32_bf16(
                                  af[mi], bfv[ni], acc[mi][ni], 0, 0, 0);

        buf  = (buf  == 2) ? 0 : buf  + 1;
        nbuf = (nbuf == 2) ? 0 : nbuf + 1;
    }
#undef GSTAGE

    int m0 = m_blk + (wave & 1) * 64;
    int n0 = n_blk + (wave >> 1) * 64;

    if constexpr (MODE == 0) {
        float* C = (float*)Cv;
        #pragma unroll
        for (int ni = 0; ni < 4; ni++) {
            int col = n0 + 16*ni + l15;
            float bv = bias ? bias[col] : 0.f;
            #pragma unroll
            for (int mi = 0; mi < 4; mi++)
                #pragma unroll
                for (int r = 0; r < 4; r++) {
                    int row = m0 + 16*mi + quad*4 + r;
                    C[(size_t)row * Cstride + col] = acc[mi][ni][r] + bv;
                }
        }
    } else {
        unsigned short* qkvo = (unsigned short*)Cv;
        int rg = n0 >> 10;             // 0=Q, 1=K, 2=V (uniform per wave)
        if (rg == 0) {
            // Q: linear bf16, pre-scaled by SCALE*log2e in fp32
            #pragma unroll
            for (int ni = 0; ni < 4; ni++) {
                int col = n0 + 16*ni + l15;
                #pragma unroll
                for (int mi = 0; mi < 4; mi++)
                    #pragma unroll
                    for (int r = 0; r < 4; r++) {
                        int row = m0 + 16*mi + quad*4 + r;
                        qkvo[(size_t)row * Cstride + col] =
                            f2bf(acc[mi][ni][r] * QSCALE_LOG2E);
                    }
            }
        } else if (rg == 1) {
            // K -> kvpack frags 0..3. Element K[key][d] of tile (bh,t) lives
            // at frag fr = ((key>>2)&1)*2 + (d>>5),
            //    lane = ((d&31)>>3)*16 + (key>>3)*4 + (key&3), elem = d&7.
            #pragma unroll
            for (int ni = 0; ni < 4; ni++) {
                int col = n0 + 16*ni + l15 - 1024;     // 0..1023
                int h = col >> 6, d = col & 63;
                int quadd = (d & 31) >> 3, e = d & 7, dhi = d >> 5;
                #pragma unroll
                for (int mi = 0; mi < 4; mi++)
                    #pragma unroll
                    for (int r = 0; r < 4; r++) {
                        int row = m0 + 16*mi + quad*4 + r;
                        int b = row >> 11, t = (row & 2047) >> 5, key = row & 31;
                        int tb = (key >> 2) & 1;
                        int l15a = ((key >> 3) << 2) + (key & 3);
                        size_t addr =
                            ((size_t)(((b*16 + h)*64 + t)*8 + tb*2 + dhi))*512
                            + (size_t)(quadd*16 + l15a)*8 + e;
                        kvpack[addr] = f2bf(acc[mi][ni][r]);
                    }
            }
        } else {
            // V -> kvpack frags 4..7. Element V[key][d] lives at
            // frag 4 + (d>>4), lane = (key>>3)*16 + (d&15), elem = key&7.
            // The 4 acc r-values are keys key0..key0+3 (key0&7 in {0,4})
            // -> 4 consecutive elems -> one aligned 8B store.
            #pragma unroll
            for (int ni = 0; ni < 4; ni++) {
                int col = n0 + 16*ni + l15 - 2048;     // 0..1023
                int h = col >> 6, d = col & 63;
                int db = d >> 4, l15v = d & 15;
                #pragma unroll
                for (int mi = 0; mi < 4; mi++) {
                    int row0 = m0 + 16*mi + quad*4;    // r = 0
                    int b = row0 >> 11, t = (row0 & 2047) >> 5, key0 = row0 & 31;
                    int quadv = key0 >> 3, e0 = key0 & 7;
                    size_t addr =
                        ((size_t)(((b*16 + h)*64 + t)*8 + 4 + db))*512
                        + (size_t)(quadv*16 + l15v)*8 + e0;
                    union { unsigned int u[2]; unsigned long long ull; } o;
                    o.u[0] = pk2bf(acc[mi][ni][0], acc[mi][ni][1]);
                    o.u[1] = pk2bf(acc[mi][ni][2], acc[mi][ni][3]);
                    *(unsigned long long*)(kvpack + addr) = o.ull;
                }
            }
        }
    }
}

// ---------------- Flash attention, unnormalized-softmax --------------------
// 4 waves/block, 32 Q rows each (2 strips A/B). KV staged per 32-key tile
// (8KiB) into a 4-buffer LDS ring via global_load_lds, prefetch distance 3,
// counted vmcnt (never 0 in steady state) + raw s_barrier. 18 MFMA per tile
// per wave (8 QK + 8 PV + 2 rowsum). Q carries SCALE*log2e; p = 2^s.

__global__ __launch_bounds__(256, 4) void attn_kernel(
    const unsigned short* __restrict__ qkv,    // [MTOT, 3072] (Q cols used)
    const unsigned short* __restrict__ kvpack, // [64 bh][64 t][8 fr][512]
    unsigned short* __restrict__ ctx)          // [MTOT, 1024]
{
    __shared__ unsigned short kvtile[4][4096];  // 4 x 8 KiB ring

    int tid  = threadIdx.x;
    int wave = tid >> 6, lane = tid & 63, quad = lane >> 4, l15 = lane & 15;
    // chunked XCD swizzle: 1024 blocks, HW round-robins blockIdx%8 across
    // XCDs -> logical block (p&7)*128 + (p>>3) puts each bh's 16 blocks on
    // ONE XCD (bijective since 1024 % 8 == 0). 8 bh/XCD = 4 MiB KV = L2.
    int p  = blockIdx.x;
    int L  = (p & 7) * 128 + (p >> 3);
    int bh = L >> 4;                 // 16 blocks per (b,h)
    int rb = L & 15;
    int b = bh >> 4, h = bh & 15;
    int i0 = rb * 128 + wave * 32;   // this wave's 32 rows (2 strips)

    const unsigned short* qbA =
        qkv + (size_t)(b*SEQ + i0 + l15) * QKVN + h*HD + quad*8;
    const unsigned short* qbB = qbA + (size_t)16 * QKVN;
    bf16x8 qA0 = *(const bf16x8*)(qbA);
    bf16x8 qA1 = *(const bf16x8*)(qbA + 32);
    bf16x8 qB0 = *(const bf16x8*)(qbB);
    bf16x8 qB1 = *(const bf16x8*)(qbB + 32);

    // flat KV stream for this bh: 64 tiles x 4096 shorts, lane-linear.
    const unsigned short* kvg = kvpack + (size_t)bh * 64 * 4096;

#define STAGE(BUF, T) do {                                                     \
        load_lds16(kvg + (size_t)(T)*4096 + tid*8,        &kvtile[BUF][tid*8]);\
        load_lds16(kvg + (size_t)(T)*4096 + 2048 + tid*8,                      \
                   &kvtile[BUF][2048 + tid*8]);                                \
    } while (0)

    const f32x4 zf = {0.f, 0.f, 0.f, 0.f};
    f32x4 oA0 = zf, oA1 = zf, oA2 = zf, oA3 = zf;
    f32x4 oB0 = zf, oB1 = zf, oB2 = zf, oB3 = zf;
    f32x4 lA = zf, lB = zf;

    bf16x8 ones;          // bf16 1.0 everywhere — B-operand for rowsum MFMA
    #pragma unroll
    for (int e = 0; e < 8; e++) ones[e] = (short)0x3F80;

#define ATTN_TILE(LK)                                                              \
    {                                                                              \
        bf16x8 k0a = *(const bf16x8*)((LK));                                       \
        bf16x8 k0b = *(const bf16x8*)((LK) + 512);                                 \
        bf16x8 k1a = *(const bf16x8*)((LK) + 1024);                                \
        bf16x8 k1b = *(const bf16x8*)((LK) + 1536);                                \
        bf16x8 v0  = *(const bf16x8*)((LK) + 2048);                                \
        bf16x8 v1  = *(const bf16x8*)((LK) + 2560);                                \
        bf16x8 v2  = *(const bf16x8*)((LK) + 3072);                                \
        bf16x8 v3  = *(const bf16x8*)((LK) + 3584);                                \
        f32x4 sA0 = __builtin_amdgcn_mfma_f32_16x16x32_bf16(k0a, qA0, zf, 0,0,0);  \
        sA0 = __builtin_amdgcn_mfma_f32_16x16x32_bf16(k0b, qA1, sA0, 0,0,0);       \
        f32x4 sA1 = __builtin_amdgcn_mfma_f32_16x16x32_bf16(k1a, qA0, zf, 0,0,0);  \
        sA1 = __builtin_amdgcn_mfma_f32_16x16x32_bf16(k1b, qA1, sA1, 0,0,0);       \
        f32x4 sB0 = __builtin_amdgcn_mfma_f32_16x16x32_bf16(k0a, qB0, zf, 0,0,0);  \
        sB0 = __builtin_amdgcn_mfma_f32_16x16x32_bf16(k0b, qB1, sB0, 0,0,0);       \
        f32x4 sB1 = __builtin_amdgcn_mfma_f32_16x16x32_bf16(k1a, qB0, zf, 0,0,0);  \
        sB1 = __builtin_amdgcn_mfma_f32_16x16x32_bf16(k1b, qB1, sB1, 0,0,0);       \
        union { unsigned int u[4]; bf16x8 v; } pkA, pkB;                           \
        pkA.u[0] = pk2bf(fast_exp2(sA0[0]), fast_exp2(sA0[1]));                    \
        pkA.u[1] = pk2bf(fast_exp2(sA0[2]), fast_exp2(sA0[3]));                    \
        pkA.u[2] = pk2bf(fast_exp2(sA1[0]), fast_exp2(sA1[1]));                    \
        pkA.u[3] = pk2bf(fast_exp2(sA1[2]), fast_exp2(sA1[3]));                    \
        pkB.u[0] = pk2bf(fast_exp2(sB0[0]), fast_exp2(sB0[1]));                    \
        pkB.u[1] = pk2bf(fast_exp2(sB0[2]), fast_exp2(sB0[3]));                    \
        pkB.u[2] = pk2bf(fast_exp2(sB1[0]), fast_exp2(sB1[1]));                    \
        pkB.u[3] = pk2bf(fast_exp2(sB1[2]), fast_exp2(sB1[3]));                    \
        lA  = __builtin_amdgcn_mfma_f32_16x16x32_bf16(pkA.v, ones, lA, 0,0,0);     \
        lB  = __builtin_amdgcn_mfma_f32_16x16x32_bf16(pkB.v, ones, lB, 0,0,0);     \
        oA0 = __builtin_amdgcn_mfma_f32_16x16x32_bf16(pkA.v, v0, oA0, 0,0,0);      \
        oA1 = __builtin_amdgcn_mfma_f32_16x16x32_bf16(pkA.v, v1, oA1, 0,0,0);      \
        oA2 = __builtin_amdgcn_mfma_f32_16x16x32_bf16(pkA.v, v2, oA2, 0,0,0);      \
        oA3 = __builtin_amdgcn_mfma_f32_16x16x32_bf16(pkA.v, v3, oA3, 0,0,0);      \
        oB0 = __builtin_amdgcn_mfma_f32_16x16x32_bf16(pkB.v, v0, oB0, 0,0,0);      \
        oB1 = __builtin_amdgcn_mfma_f32_16x16x32_bf16(pkB.v, v1, oB1, 0,0,0);      \
        oB2 = __builtin_amdgcn_mfma_f32_16x16x32_bf16(pkB.v, v2, oB2, 0,0,0);      \
        oB3 = __builtin_amdgcn_mfma_f32_16x16x32_bf16(pkB.v, v3, oB3, 0,0,0);      \
    }

    // drain Q loads so loop vmcnt counting sees only STAGE ops
    asm volatile("s_waitcnt vmcnt(0)" ::: "memory");

    STAGE(0, 0); STAGE(1, 1); STAGE(2, 2);      // 6 loads in flight

    const unsigned short* lds0 = &kvtile[0][lane*8];

    // main loop: tiles 0..60; STAGE(t+3) issued each iter (last = tile 63)
    for (int t = 0; t < 61; ++t) {
        SYNC(4);                                 // tile t landed; 4 still flying
        STAGE((t + 3) & 3, t + 3);
        ATTN_TILE(lds0 + (t & 3) * 4096);
    }
    // tail: tiles 61 (vmcnt 4: 62,63 flying), 62 (vmcnt 2), 63 (vmcnt 0)
    SYNC(4); ATTN_TILE(lds0 + 1 * 4096);
    SYNC(2); ATTN_TILE(lds0 + 2 * 4096);
    SYNC(0); ATTN_TILE(lds0 + 3 * 4096);

    // epilogue: l*[r] = full row sum for row quad*4+r (same in every lane)
    #pragma unroll
    for (int r = 0; r < 4; r++) {
        float invA = 1.f / lA[r];
        float invB = 1.f / lB[r];
        int rowA = b*SEQ + i0 + quad*4 + r;
        size_t baseA = (size_t)rowA * CDIM + h*HD + l15;
        size_t baseB = baseA + (size_t)16 * CDIM;
        ctx[baseA]      = f2bf(oA0[r] * invA);
        ctx[baseA + 16] = f2bf(oA1[r] * invA);
        ctx[baseA + 32] = f2bf(oA2[r] * invA);
        ctx[baseA + 48] = f2bf(oA3[r] * invA);
        ctx[baseB]      = f2bf(oB0[r] * invB);
        ctx[baseB + 16] = f2bf(oB1[r] * invB);
        ctx[baseB + 32] = f2bf(oB2[r] * invB);
        ctx[baseB + 48] = f2bf(oB3[r] * invB);
    }
#undef STAGE
#undef ATTN_TILE
}

// ---------------------------------------------------------------------------
extern "C" void kernel_launch(void* const* d_in, const int* in_sizes, int n_in,
                              void* d_out, int out_size, void* d_ws, size_t ws_size,
                              hipStream_t stream)
{
    const float* x      = (const float*)d_in[0]; // [8192,1024] fp32
    const float* w_qkv  = (const float*)d_in[1]; // [1024,3072] fp32
    const float* w_proj = (const float*)d_in[2]; // [1024,1024] fp32
    const float* b_proj = (const float*)d_in[3]; // [1024]      fp32
    float* out = (float*)d_out;                  // [8192,1024] fp32

    char* ws = (char*)d_ws;                                      // 104 MiB used
    unsigned short* qkv    = (unsigned short*)(ws);              // [0,48M)
    unsigned short* ctx    = (unsigned short*)(ws + 50331648);   // [48M,64M)
    unsigned short* xb     = ctx;    // alias: xb consumed by gemm1 before attn
                                     // writes ctx
    unsigned short* kvpack = (unsigned short*)(ws + 67108864);   // [64M,96M)
    unsigned short* wqkvT  = (unsigned short*)(ws + 100663296);  // [96M,102M)
    unsigned short* wprojT = (unsigned short*)(ws + 106954752);  // [102M,104M)

    dim3 tb(32, 8);
    transpose_f32_to_bf16<<<dim3(QKVN/32, CDIM/32), tb, 0, stream>>>(
        w_qkv, wqkvT, QKVN, CDIM);
    transpose_f32_to_bf16<<<dim3(CDIM/32, CDIM/32), tb, 0, stream>>>(
        w_proj, wprojT, CDIM, CDIM);

    // xb = bf16(x)
    convert_f32_bf16<<<dim3(MTOT*CDIM/2048), 256, 0, stream>>>(x, xb);

    // fused QKV GEMM: Q -> qkv linear (scaled), K/V -> kvpack fragment order
    // grid = (3072/128) x (8192/128) = 24 x 64 = 1536 blocks (1536 % 8 == 0)
    gemm_lds<1, QKVN/128><<<dim3((QKVN/128)*(MTOT/128)), 256, 0, stream>>>(
        xb, wqkvT, qkv, kvpack, nullptr, CDIM, QKVN);

    // flash attention -> ctx [8192, 1024] bf16 (overwrites xb region)
    attn_kernel<<<dim3(BN * NH * (SEQ/128)), 256, 0, stream>>>(
        qkv, kvpack, ctx);

    // out = ctx @ wprojT + b_proj   (fp32 out)
    // grid = (1024/128) x (8192/128) = 8 x 64 = 512 blocks (512 % 8 == 0)
    gemm_lds<0, CDIM/128><<<dim3((CDIM/128)*(MTOT/128)), 256, 0, stream>>>(
        ctx, wprojT, out, nullptr, b_proj, CDIM, CDIM);
}

// Round 8
// 268.348 us; speedup vs baseline: 1.3197x; 1.0277x over previous
//
#include <hip/hip_runtime.h>
#include <hip/hip_bf16.h>

// Attention_919123001813 — B=4, N=2048, DIM=1024, H=16, HD=64, SCALE=1/8
// Round 18: R17's profile exposed a real 6.29M-cycle LDS bank conflict in
// gemm_lds (the 912us dispatch itself is a profiler queue-stall artifact:
// all counters diluted by the same ~10x; real ~90us @ ~97% combined issue).
// Cause: fragment ds_read_b128 at row*64B+quad*16B -> same-quad lanes with
// rows differing by 2 alias -> 8-way conflict (2.94x per read, m136).
// Fix (rule #21: both-sides-or-neither with global_load_lds): LDS dest stays
// linear; pre-swizzle the GLOBAL source chunk (tid&3)^((tid>>3)&3) (within-
// row 16B permutation -> same cache lines) and XOR the read base with
// quad^((l15>>1)&3). (row>>1)&3 is invariant across all fragment offsets, so
// the swizzle folds into one-time pointer setup: ZERO per-loop VALU.
// Result: all 8 bank granules covered per quad -> 2-way (free).
// Applied to both GEMMs; attn (0 conflicts) and all epilogues unchanged.

typedef short bf16x8 __attribute__((ext_vector_type(8)));
typedef float f32x4  __attribute__((ext_vector_type(4)));

#define BN   4
#define SEQ  2048
#define CDIM 1024
#define NH   16
#define HD   64
#define QKVN 3072
#define MTOT 8192   // BN*SEQ
// SCALE * log2(e) — folded into Q columns of the QKV GEMM output (fp32).
#define QSCALE_LOG2E 0.18033688011112042f

static __device__ __forceinline__ unsigned short f2bf(float f){
    union { float f; unsigned int i; } v; v.f = f;
    unsigned int r = v.i + 0x7FFFu + ((v.i >> 16) & 1u);   // RNE
    return (unsigned short)(r >> 16);
}

// two fp32 -> one dword of packed bf16 (RNE). gfx950: single v_cvt_pk_bf16_f32.
static __device__ __forceinline__ unsigned int pk2bf(float a, float b){
#if __has_builtin(__builtin_amdgcn_cvt_pk_bf16_f32)
    auto r = __builtin_amdgcn_cvt_pk_bf16_f32(a, b);
    unsigned int u; __builtin_memcpy(&u, &r, 4); return u;
#else
    return (unsigned int)f2bf(a) | ((unsigned int)f2bf(b) << 16);
#endif
}

// raw 2^x (v_exp_f32). Q already carries the SCALE*log2e factor.
static __device__ __forceinline__ float fast_exp2(float x){
#if __has_builtin(__builtin_amdgcn_exp2f)
    return __builtin_amdgcn_exp2f(x);
#else
    return __expf(x * 0.69314718055994531f);
#endif
}

typedef __attribute__((address_space(3))) unsigned int        as3_uint;
typedef const __attribute__((address_space(1))) unsigned int  as1_uint;
static __device__ __forceinline__ void load_lds16(
    const unsigned short* g, unsigned short* l)
{
    __builtin_amdgcn_global_load_lds((as1_uint*)g, (as3_uint*)l, 16, 0, 0);
}

// counted-vmcnt sync: own loads retired to <=N, then publish via barrier.
#define SYNC(N) do {                                                           \
        __builtin_amdgcn_sched_barrier(0);                                     \
        asm volatile("s_waitcnt vmcnt(" #N ")" ::: "memory");                  \
        __builtin_amdgcn_s_barrier();                                          \
        __builtin_amdgcn_sched_barrier(0);                                     \
    } while (0)

// ---------------- elementwise fp32 -> bf16 (8 elems/thread) ----------------
__global__ __launch_bounds__(256) void convert_f32_bf16(
    const float* __restrict__ in, unsigned short* __restrict__ out)
{
    size_t i = ((size_t)blockIdx.x * 256 + threadIdx.x) * 8;
    f32x4 a = *(const f32x4*)(in + i);
    f32x4 b = *(const f32x4*)(in + i + 4);
    union { unsigned int u[4]; bf16x8 v; } o;
    o.u[0] = pk2bf(a[0], a[1]); o.u[1] = pk2bf(a[2], a[3]);
    o.u[2] = pk2bf(b[0], b[1]); o.u[3] = pk2bf(b[2], b[3]);
    *(bf16x8*)(out + i) = o.v;
}

// ---------------- 32x32 tiled transpose: fp32 in -> bf16 out ---------------
__global__ __launch_bounds__(256) void transpose_f32_to_bf16(
    const float* __restrict__ in, unsigned short* __restrict__ out,
    int in_rs, int out_rs)
{
    __shared__ unsigned short tile[32][33];
    int c0 = blockIdx.x * 32, r0 = blockIdx.y * 32;
    int tx = threadIdx.x, ty = threadIdx.y;
    #pragma unroll
    for (int j = 0; j < 4; j++)
        tile[ty + 8*j][tx] = f2bf(in[(long long)(r0 + ty + 8*j) * in_rs + c0 + tx]);
    __syncthreads();
    #pragma unroll
    for (int j = 0; j < 4; j++)
        out[(long long)(c0 + ty + 8*j) * out_rs + r0 + tx] = tile[tx][ty + 8*j];
}

// ---------------- m97-style GEMM, counted-vmcnt 3-ring, swizzled LDS --------
// MODE 0: C = A@BT^T + bias, fp32 out (proj GEMM).
// MODE 1: fused QKV: cols [0,1024) -> qkv linear bf16, scaled by
//         SCALE*log2e (fp32, pre-round); cols [1024,2048) -> kvpack K frags;
//         cols [2048,3072) -> kvpack V frags.
// NX = grid width in 128-tiles (compile-time for cheap div in swizzle).
template<int MODE, int NX>
__global__ __launch_bounds__(256) void gemm_lds(
    const unsigned short* __restrict__ A,    // [M,K] bf16
    const unsigned short* __restrict__ BT,   // [N,K] bf16
    void* __restrict__ Cv,                   // MODE0: float*; MODE1: ushort* qkv
    unsigned short* __restrict__ kvpack,     // MODE1 only
    const float* __restrict__ bias,          // MODE0 only (or nullptr)
    int K, int Cstride)
{
    __shared__ unsigned short a_lds[3][4096];   // 3 x 8 KiB ring (A)
    __shared__ unsigned short b_lds[3][4096];   // 3 x 8 KiB ring (B)

    int tid  = threadIdx.x;
    int wave = tid >> 6, lane = tid & 63, quad = lane >> 4, l15 = lane & 15;

    // bijective chunked XCD swizzle (nwg % 8 == 0): XCD x gets logical
    // blocks [x*cpx, (x+1)*cpx) -> contiguous m-rows share the B panel in L2.
    int nwg = gridDim.x;
    int cpx = nwg >> 3;
    int bid = blockIdx.x;
    int swz = (bid & 7) * cpx + (bid >> 3);
    int m_blk = (swz / NX) * 128, n_blk = (swz % NX) * 128;

    // bank-conflict swizzle: LDS physical chunk (row, c) holds global chunk
    // c ^ ((row>>1)&3). Stage side: thread tid = (row = tid>>2, c = tid&3)
    // fetches global chunk (tid&3)^((tid>>3)&3) (within-row 16B permutation;
    // same cache lines). Read side: want global chunk `quad` of row
    // (..+l15+16i) -> read physical chunk quad^((l15>>1)&3) (invariant over
    // all fragment offsets). Zero per-loop cost; 8-way -> 2-way (free).
    int csrc = ((tid & 3) ^ ((tid >> 3) & 3)) * 8;
    int crd  = (quad ^ ((l15 >> 1) & 3)) * 8;

    const unsigned short* ag = A  + (size_t)(m_blk + (tid >> 2)) * K + csrc;
    const unsigned short* bg = BT + (size_t)(n_blk + (tid >> 2)) * K + csrc;
    const size_t row64 = (size_t)64 * K;

#define GSTAGE(BUF, T) do {                                                    \
        const unsigned short* ag_ = ag + (size_t)(T)*32;                       \
        const unsigned short* bg_ = bg + (size_t)(T)*32;                       \
        load_lds16(ag_,         &a_lds[BUF][tid*8]);                           \
        load_lds16(ag_ + row64, &a_lds[BUF][2048 + tid*8]);                    \
        load_lds16(bg_,         &b_lds[BUF][tid*8]);                           \
        load_lds16(bg_ + row64, &b_lds[BUF][2048 + tid*8]);                    \
    } while (0)

    const unsigned short* afr = &a_lds[0][((wave & 1)*64 + l15)*32 + crd];
    const unsigned short* bfr = &b_lds[0][((wave >> 1)*64 + l15)*32 + crd];

    f32x4 acc[4][4];
    #pragma unroll
    for (int i = 0; i < 4; i++)
        #pragma unroll
        for (int j = 0; j < 4; j++)
            acc[i][j] = f32x4{0.f, 0.f, 0.f, 0.f};

    int nk = K >> 5;                      // K-steps of 32
    GSTAGE(0, 0);
    GSTAGE(1, 1);                         // 8 loads in flight (tiles 0,1)

    int buf = 0, nbuf = 2;                // buf = t%3; nbuf = (t+2)%3
    for (int t = 0; t < nk; ++t) {
        if (t + 2 < nk) {
            SYNC(4);                      // tile t landed; tile t+1 flying
            GSTAGE(nbuf, t + 2);          // into buffer (t-1)%3 (reads done)
        } else if (t + 1 < nk) {
            SYNC(4);                      // tile t landed; t+1 flying
        } else {
            SYNC(0);                      // last tile landed
        }

        int bo = buf * 4096;
        bf16x8 af[4], bfv[4];
        #pragma unroll
        for (int i = 0; i < 4; i++) af[i]  = *(const bf16x8*)(afr + bo + 16*i*32);
        #pragma unroll
        for (int i = 0; i < 4; i++) bfv[i] = *(const bf16x8*)(bfr + bo + 16*i*32);

        #pragma unroll
        for (int mi = 0; mi < 4; mi++)
            #pragma unroll
            for (int ni = 0; ni < 4; ni++)
                acc[mi][ni] = __builtin_amdgcn_mfma_f32_16x16x32_bf16(
                                  af[mi], bfv[ni], acc[mi][ni], 0, 0, 0);

        buf  = (buf  == 2) ? 0 : buf  + 1;
        nbuf = (nbuf == 2) ? 0 : nbuf + 1;
    }
#undef GSTAGE

    int m0 = m_blk + (wave & 1) * 64;
    int n0 = n_blk + (wave >> 1) * 64;

    if constexpr (MODE == 0) {
        float* C = (float*)Cv;
        #pragma unroll
        for (int ni = 0; ni < 4; ni++) {
            int col = n0 + 16*ni + l15;
            float bv = bias ? bias[col] : 0.f;
            #pragma unroll
            for (int mi = 0; mi < 4; mi++)
                #pragma unroll
                for (int r = 0; r < 4; r++) {
                    int row = m0 + 16*mi + quad*4 + r;
                    C[(size_t)row * Cstride + col] = acc[mi][ni][r] + bv;
                }
        }
    } else {
        unsigned short* qkvo = (unsigned short*)Cv;
        int rg = n0 >> 10;             // 0=Q, 1=K, 2=V (uniform per wave)
        if (rg == 0) {
            // Q: linear bf16, pre-scaled by SCALE*log2e in fp32
            #pragma unroll
            for (int ni = 0; ni < 4; ni++) {
                int col = n0 + 16*ni + l15;
                #pragma unroll
                for (int mi = 0; mi < 4; mi++)
                    #pragma unroll
                    for (int r = 0; r < 4; r++) {
                        int row = m0 + 16*mi + quad*4 + r;
                        qkvo[(size_t)row * Cstride + col] =
                            f2bf(acc[mi][ni][r] * QSCALE_LOG2E);
                    }
            }
        } else if (rg == 1) {
            // K -> kvpack frags 0..3. Element K[key][d] of tile (bh,t) lives
            // at frag fr = ((key>>2)&1)*2 + (d>>5),
            //    lane = ((d&31)>>3)*16 + (key>>3)*4 + (key&3), elem = d&7.
            #pragma unroll
            for (int ni = 0; ni < 4; ni++) {
                int col = n0 + 16*ni + l15 - 1024;     // 0..1023
                int h = col >> 6, d = col & 63;
                int quadd = (d & 31) >> 3, e = d & 7, dhi = d >> 5;
                #pragma unroll
                for (int mi = 0; mi < 4; mi++)
                    #pragma unroll
                    for (int r = 0; r < 4; r++) {
                        int row = m0 + 16*mi + quad*4 + r;
                        int b = row >> 11, t = (row & 2047) >> 5, key = row & 31;
                        int tb = (key >> 2) & 1;
                        int l15a = ((key >> 3) << 2) + (key & 3);
                        size_t addr =
                            ((size_t)(((b*16 + h)*64 + t)*8 + tb*2 + dhi))*512
                            + (size_t)(quadd*16 + l15a)*8 + e;
                        kvpack[addr] = f2bf(acc[mi][ni][r]);
                    }
            }
        } else {
            // V -> kvpack frags 4..7. Element V[key][d] lives at
            // frag 4 + (d>>4), lane = (key>>3)*16 + (d&15), elem = key&7.
            // The 4 acc r-values are keys key0..key0+3 (key0&7 in {0,4})
            // -> 4 consecutive elems -> one aligned 8B store.
            #pragma unroll
            for (int ni = 0; ni < 4; ni++) {
                int col = n0 + 16*ni + l15 - 2048;     // 0..1023
                int h = col >> 6, d = col & 63;
                int db = d >> 4, l15v = d & 15;
                #pragma unroll
                for (int mi = 0; mi < 4; mi++) {
                    int row0 = m0 + 16*mi + quad*4;    // r = 0
                    int b = row0 >> 11, t = (row0 & 2047) >> 5, key0 = row0 & 31;
                    int quadv = key0 >> 3, e0 = key0 & 7;
                    size_t addr =
                        ((size_t)(((b*16 + h)*64 + t)*8 + 4 + db))*512
                        + (size_t)(quadv*16 + l15v)*8 + e0;
                    union { unsigned int u[2]; unsigned long long ull; } o;
                    o.u[0] = pk2bf(acc[mi][ni][0], acc[mi][ni][1]);
                    o.u[1] = pk2bf(acc[mi][ni][2], acc[mi][ni][3]);
                    *(unsigned long long*)(kvpack + addr) = o.ull;
                }
            }
        }
    }
}

// ---------------- Flash attention, unnormalized-softmax --------------------
// 4 waves/block, 32 Q rows each (2 strips A/B). KV staged per 32-key tile
// (8KiB) into a 4-buffer LDS ring via global_load_lds, prefetch distance 3,
// counted vmcnt (never 0 in steady state) + raw s_barrier. 18 MFMA per tile
// per wave (8 QK + 8 PV + 2 rowsum). Q carries SCALE*log2e; p = 2^s.

__global__ __launch_bounds__(256, 4) void attn_kernel(
    const unsigned short* __restrict__ qkv,    // [MTOT, 3072] (Q cols used)
    const unsigned short* __restrict__ kvpack, // [64 bh][64 t][8 fr][512]
    unsigned short* __restrict__ ctx)          // [MTOT, 1024]
{
    __shared__ unsigned short kvtile[4][4096];  // 4 x 8 KiB ring

    int tid  = threadIdx.x;
    int wave = tid >> 6, lane = tid & 63, quad = lane >> 4, l15 = lane & 15;
    // chunked XCD swizzle: 1024 blocks, HW round-robins blockIdx%8 across
    // XCDs -> logical block (p&7)*128 + (p>>3) puts each bh's 16 blocks on
    // ONE XCD (bijective since 1024 % 8 == 0). 8 bh/XCD = 4 MiB KV = L2.
    int p  = blockIdx.x;
    int L  = (p & 7) * 128 + (p >> 3);
    int bh = L >> 4;                 // 16 blocks per (b,h)
    int rb = L & 15;
    int b = bh >> 4, h = bh & 15;
    int i0 = rb * 128 + wave * 32;   // this wave's 32 rows (2 strips)

    const unsigned short* qbA =
        qkv + (size_t)(b*SEQ + i0 + l15) * QKVN + h*HD + quad*8;
    const unsigned short* qbB = qbA + (size_t)16 * QKVN;
    bf16x8 qA0 = *(const bf16x8*)(qbA);
    bf16x8 qA1 = *(const bf16x8*)(qbA + 32);
    bf16x8 qB0 = *(const bf16x8*)(qbB);
    bf16x8 qB1 = *(const bf16x8*)(qbB + 32);

    // flat KV stream for this bh: 64 tiles x 4096 shorts, lane-linear.
    const unsigned short* kvg = kvpack + (size_t)bh * 64 * 4096;

#define STAGE(BUF, T) do {                                                     \
        load_lds16(kvg + (size_t)(T)*4096 + tid*8,        &kvtile[BUF][tid*8]);\
        load_lds16(kvg + (size_t)(T)*4096 + 2048 + tid*8,                      \
                   &kvtile[BUF][2048 + tid*8]);                                \
    } while (0)

    const f32x4 zf = {0.f, 0.f, 0.f, 0.f};
    f32x4 oA0 = zf, oA1 = zf, oA2 = zf, oA3 = zf;
    f32x4 oB0 = zf, oB1 = zf, oB2 = zf, oB3 = zf;
    f32x4 lA = zf, lB = zf;

    bf16x8 ones;          // bf16 1.0 everywhere — B-operand for rowsum MFMA
    #pragma unroll
    for (int e = 0; e < 8; e++) ones[e] = (short)0x3F80;

#define ATTN_TILE(LK)                                                              \
    {                                                                              \
        bf16x8 k0a = *(const bf16x8*)((LK));                                       \
        bf16x8 k0b = *(const bf16x8*)((LK) + 512);                                 \
        bf16x8 k1a = *(const bf16x8*)((LK) + 1024);                                \
        bf16x8 k1b = *(const bf16x8*)((LK) + 1536);                                \
        bf16x8 v0  = *(const bf16x8*)((LK) + 2048);                                \
        bf16x8 v1  = *(const bf16x8*)((LK) + 2560);                                \
        bf16x8 v2  = *(const bf16x8*)((LK) + 3072);                                \
        bf16x8 v3  = *(const bf16x8*)((LK) + 3584);                                \
        f32x4 sA0 = __builtin_amdgcn_mfma_f32_16x16x32_bf16(k0a, qA0, zf, 0,0,0);  \
        sA0 = __builtin_amdgcn_mfma_f32_16x16x32_bf16(k0b, qA1, sA0, 0,0,0);       \
        f32x4 sA1 = __builtin_amdgcn_mfma_f32_16x16x32_bf16(k1a, qA0, zf, 0,0,0);  \
        sA1 = __builtin_amdgcn_mfma_f32_16x16x32_bf16(k1b, qA1, sA1, 0,0,0);       \
        f32x4 sB0 = __builtin_amdgcn_mfma_f32_16x16x32_bf16(k0a, qB0, zf, 0,0,0);  \
        sB0 = __builtin_amdgcn_mfma_f32_16x16x32_bf16(k0b, qB1, sB0, 0,0,0);       \
        f32x4 sB1 = __builtin_amdgcn_mfma_f32_16x16x32_bf16(k1a, qB0, zf, 0,0,0);  \
        sB1 = __builtin_amdgcn_mfma_f32_16x16x32_bf16(k1b, qB1, sB1, 0,0,0);       \
        union { unsigned int u[4]; bf16x8 v; } pkA, pkB;                           \
        pkA.u[0] = pk2bf(fast_exp2(sA0[0]), fast_exp2(sA0[1]));                    \
        pkA.u[1] = pk2bf(fast_exp2(sA0[2]), fast_exp2(sA0[3]));                    \
        pkA.u[2] = pk2bf(fast_exp2(sA1[0]), fast_exp2(sA1[1]));                    \
        pkA.u[3] = pk2bf(fast_exp2(sA1[2]), fast_exp2(sA1[3]));                    \
        pkB.u[0] = pk2bf(fast_exp2(sB0[0]), fast_exp2(sB0[1]));                    \
        pkB.u[1] = pk2bf(fast_exp2(sB0[2]), fast_exp2(sB0[3]));                    \
        pkB.u[2] = pk2bf(fast_exp2(sB1[0]), fast_exp2(sB1[1]));                    \
        pkB.u[3] = pk2bf(fast_exp2(sB1[2]), fast_exp2(sB1[3]));                    \
        lA  = __builtin_amdgcn_mfma_f32_16x16x32_bf16(pkA.v, ones, lA, 0,0,0);     \
        lB  = __builtin_amdgcn_mfma_f32_16x16x32_bf16(pkB.v, ones, lB, 0,0,0);     \
        oA0 = __builtin_amdgcn_mfma_f32_16x16x32_bf16(pkA.v, v0, oA0, 0,0,0);      \
        oA1 = __builtin_amdgcn_mfma_f32_16x16x32_bf16(pkA.v, v1, oA1, 0,0,0);      \
        oA2 = __builtin_amdgcn_mfma_f32_16x16x32_bf16(pkA.v, v2, oA2, 0,0,0);      \
        oA3 = __builtin_amdgcn_mfma_f32_16x16x32_bf16(pkA.v, v3, oA3, 0,0,0);      \
        oB0 = __builtin_amdgcn_mfma_f32_16x16x32_bf16(pkB.v, v0, oB0, 0,0,0);      \
        oB1 = __builtin_amdgcn_mfma_f32_16x16x32_bf16(pkB.v, v1, oB1, 0,0,0);      \
        oB2 = __builtin_amdgcn_mfma_f32_16x16x32_bf16(pkB.v, v2, oB2, 0,0,0);      \
        oB3 = __builtin_amdgcn_mfma_f32_16x16x32_bf16(pkB.v, v3, oB3, 0,0,0);      \
    }

    // drain Q loads so loop vmcnt counting sees only STAGE ops
    asm volatile("s_waitcnt vmcnt(0)" ::: "memory");

    STAGE(0, 0); STAGE(1, 1); STAGE(2, 2);      // 6 loads in flight

    const unsigned short* lds0 = &kvtile[0][lane*8];

    // main loop: tiles 0..60; STAGE(t+3) issued each iter (last = tile 63)
    for (int t = 0; t < 61; ++t) {
        SYNC(4);                                 // tile t landed; 4 still flying
        STAGE((t + 3) & 3, t + 3);
        ATTN_TILE(lds0 + (t & 3) * 4096);
    }
    // tail: tiles 61 (vmcnt 4: 62,63 flying), 62 (vmcnt 2), 63 (vmcnt 0)
    SYNC(4); ATTN_TILE(lds0 + 1 * 4096);
    SYNC(2); ATTN_TILE(lds0 + 2 * 4096);
    SYNC(0); ATTN_TILE(lds0 + 3 * 4096);

    // epilogue: l*[r] = full row sum for row quad*4+r (same in every lane)
    #pragma unroll
    for (int r = 0; r < 4; r++) {
        float invA = 1.f / lA[r];
        float invB = 1.f / lB[r];
        int rowA = b*SEQ + i0 + quad*4 + r;
        size_t baseA = (size_t)rowA * CDIM + h*HD + l15;
        size_t baseB = baseA + (size_t)16 * CDIM;
        ctx[baseA]      = f2bf(oA0[r] * invA);
        ctx[baseA + 16] = f2bf(oA1[r] * invA);
        ctx[baseA + 32] = f2bf(oA2[r] * invA);
        ctx[baseA + 48] = f2bf(oA3[r] * invA);
        ctx[baseB]      = f2bf(oB0[r] * invB);
        ctx[baseB + 16] = f2bf(oB1[r] * invB);
        ctx[baseB + 32] = f2bf(oB2[r] * invB);
        ctx[baseB + 48] = f2bf(oB3[r] * invB);
    }
#undef STAGE
#undef ATTN_TILE
}

// ---------------------------------------------------------------------------
extern "C" void kernel_launch(void* const* d_in, const int* in_sizes, int n_in,
                              void* d_out, int out_size, void* d_ws, size_t ws_size,
                              hipStream_t stream)
{
    const float* x      = (const float*)d_in[0]; // [8192,1024] fp32
    const float* w_qkv  = (const float*)d_in[1]; // [1024,3072] fp32
    const float* w_proj = (const float*)d_in[2]; // [1024,1024] fp32
    const float* b_proj = (const float*)d_in[3]; // [1024]      fp32
    float* out = (float*)d_out;                  // [8192,1024] fp32

    char* ws = (char*)d_ws;                                      // 104 MiB used
    unsigned short* qkv    = (unsigned short*)(ws);              // [0,48M)
    unsigned short* ctx    = (unsigned short*)(ws + 50331648);   // [48M,64M)
    unsigned short* xb     = ctx;    // alias: xb consumed by gemm1 before attn
                                     // writes ctx
    unsigned short* kvpack = (unsigned short*)(ws + 67108864);   // [64M,96M)
    unsigned short* wqkvT  = (unsigned short*)(ws + 100663296);  // [96M,102M)
    unsigned short* wprojT = (unsigned short*)(ws + 106954752);  // [102M,104M)

    dim3 tb(32, 8);
    transpose_f32_to_bf16<<<dim3(QKVN/32, CDIM/32), tb, 0, stream>>>(
        w_qkv, wqkvT, QKVN, CDIM);
    transpose_f32_to_bf16<<<dim3(CDIM/32, CDIM/32), tb, 0, stream>>>(
        w_proj, wprojT, CDIM, CDIM);

    // xb = bf16(x)
    convert_f32_bf16<<<dim3(MTOT*CDIM/2048), 256, 0, stream>>>(x, xb);

    // fused QKV GEMM: Q -> qkv linear (scaled), K/V -> kvpack fragment order
    // grid = (3072/128) x (8192/128) = 24 x 64 = 1536 blocks (1536 % 8 == 0)
    gemm_lds<1, QKVN/128><<<dim3((QKVN/128)*(MTOT/128)), 256, 0, stream>>>(
        xb, wqkvT, qkv, kvpack, nullptr, CDIM, QKVN);

    // flash attention -> ctx [8192, 1024] bf16 (overwrites xb region)
    attn_kernel<<<dim3(BN * NH * (SEQ/128)), 256, 0, stream>>>(
        qkv, kvpack, ctx);

    // out = ctx @ wprojT + b_proj   (fp32 out)
    // grid = (1024/128) x (8192/128) = 8 x 64 = 512 blocks (512 % 8 == 0)
    gemm_lds<0, CDIM/128><<<dim3((CDIM/128)*(MTOT/128)), 256, 0, stream>>>(
        ctx, wprojT, out, nullptr, b_proj, CDIM, CDIM);
}